// Round 2
// baseline (893.955 us; speedup 1.0000x reference)
//
#include <hip/hip_runtime.h>
#include <math.h>

#define NB 8
#define NC 64
#define NH 256
#define NW 256
#define NHW 65536
#define NM 32
#define NPS 4194304   // C*H*W per sample
#define GN_EPS 1e-5f
#define OMEGA 0.0245436926061703f  // 2*pi/256

typedef short shortx8 __attribute__((ext_vector_type(8)));
typedef float floatx4 __attribute__((ext_vector_type(4)));

__device__ __forceinline__ float gelu_f(float v) {
    return 0.5f * v * (1.0f + erff(v * 0.7071067811865475f));
}

__device__ __forceinline__ unsigned short f2bf(float f) {
    unsigned u = __builtin_bit_cast(unsigned, f);
    u = (u + 0x7fffu + ((u >> 16) & 1u)) >> 16;
    return (unsigned short)u;
}

__device__ __forceinline__ float bf2f(unsigned short u) {
    return __builtin_bit_cast(float, ((unsigned)u) << 16);
}

// ---------------- K0: zero GN accumulators, compute FiLM gamma/beta per (b,c)
__global__ void k0_init(const float* __restrict__ t_in,
                        const float* __restrict__ gamma_w, const float* __restrict__ gamma_b,
                        const float* __restrict__ beta_w, const float* __restrict__ beta_b,
                        float* __restrict__ gn_acc, float* __restrict__ gamma_bc,
                        float* __restrict__ beta_bc) {
    int t = threadIdx.x;
    if (t < 32) gn_acc[t] = 0.f;
    for (int idx = t; idx < NB * NC; idx += 256) {
        int b = idx >> 6, o = idx & 63;
        float g = gamma_b[o], be = beta_b[o];
        for (int c = 0; c < NC; ++c) {
            float tv = t_in[b * NC + c];
            g += gamma_w[o * NC + c] * tv;
            be += beta_w[o * NC + c] * tv;
        }
        gamma_bc[idx] = g;
        beta_bc[idx] = be;
    }
}

// ---------------- K1: real DFT along W, keep kx 0..31.  Xw[bc][h][kx]
__global__ __launch_bounds__(128) void k1_dftw(const float* __restrict__ x,
                                               float* __restrict__ xw_re,
                                               float* __restrict__ xw_im) {
    __shared__ float xs[32 * 257];
    int blk = blockIdx.x;        // 4096 = 512 bc * 8 hchunks
    int bc = blk >> 3;
    int h0 = (blk & 7) * 32;
    const float* src = x + (size_t)bc * NHW + (size_t)h0 * NW;
    for (int idx = threadIdx.x; idx < 2048; idx += 128) {
        float4 v = ((const float4*)src)[idx];
        int r = idx >> 6;
        int w = (idx & 63) * 4;
        float* d = &xs[r * 257 + w];
        d[0] = v.x; d[1] = v.y; d[2] = v.z; d[3] = v.w;
    }
    __syncthreads();
    int t = threadIdx.x;
    int row = t >> 2;       // 0..31
    int kgrp = t & 3;       // kx = kgrp*8 + j
    float cd[8], sd[8], cc[8], ss[8], ar[8], ai[8];
#pragma unroll
    for (int j = 0; j < 8; ++j) {
        int kx = kgrp * 8 + j;
        sincosf(OMEGA * (float)kx, &sd[j], &cd[j]);
        cc[j] = 1.f; ss[j] = 0.f; ar[j] = 0.f; ai[j] = 0.f;
    }
    const float* xrow = &xs[row * 257];
    for (int w = 0; w < 256; ++w) {
        float xv = xrow[w];
#pragma unroll
        for (int j = 0; j < 8; ++j) {
            ar[j] += xv * cc[j];        // e^{-i th}: re += x cos
            ai[j] -= xv * ss[j];        // im -= x sin
            float c2 = cc[j] * cd[j] - ss[j] * sd[j];
            ss[j] = ss[j] * cd[j] + cc[j] * sd[j];
            cc[j] = c2;
        }
    }
    size_t rowg = (size_t)bc * NH + h0 + row;
#pragma unroll
    for (int j = 0; j < 8; ++j) {
        int kx = kgrp * 8 + j;
        xw_re[rowg * NM + kx] = ar[j];
        xw_im[rowg * NM + kx] = ai[j];
    }
}

// ---------------- K2: complex DFT along H at kept rows.  Xf[bc][j64][kx]
__global__ __launch_bounds__(256) void k2_dfth(const float* __restrict__ xw_re,
                                               const float* __restrict__ xw_im,
                                               float* __restrict__ xf_re,
                                               float* __restrict__ xf_im) {
    __shared__ float xr_l[NH * NM];
    __shared__ float xi_l[NH * NM];
    int bc = blockIdx.x;
    size_t base = (size_t)bc * NH * NM;
    for (int idx = threadIdx.x; idx < NH * NM / 4; idx += 256) {
        ((float4*)xr_l)[idx] = ((const float4*)(xw_re + base))[idx];
        ((float4*)xi_l)[idx] = ((const float4*)(xw_im + base))[idx];
    }
    __syncthreads();
    int t = threadIdx.x;
    int kx = t & 31, jgrp = t >> 5;
    float cd[8], sd[8], cc[8], ss[8], ar[8], ai[8];
#pragma unroll
    for (int jj = 0; jj < 8; ++jj) {
        int j = jgrp * 8 + jj;
        int f = (j < 32) ? j : 192 + j;     // actual row frequency
        sincosf(OMEGA * (float)f, &sd[jj], &cd[jj]);
        cc[jj] = 1.f; ss[jj] = 0.f; ar[jj] = 0.f; ai[jj] = 0.f;
    }
    for (int h = 0; h < 256; ++h) {
        float xr = xr_l[h * NM + kx], xi = xi_l[h * NM + kx];
#pragma unroll
        for (int jj = 0; jj < 8; ++jj) {
            // (xr + i xi) * (c - i s)
            ar[jj] += xr * cc[jj] + xi * ss[jj];
            ai[jj] += xi * cc[jj] - xr * ss[jj];
            float c2 = cc[jj] * cd[jj] - ss[jj] * sd[jj];
            ss[jj] = ss[jj] * cd[jj] + cc[jj] * sd[jj];
            cc[jj] = c2;
        }
    }
    size_t ob = (size_t)bc * 2048;
#pragma unroll
    for (int jj = 0; jj < 8; ++jj) {
        int j = jgrp * 8 + jj;
        xf_re[ob + j * 32 + kx] = ar[jj];
        xf_im[ob + j * 32 + kx] = ai[jj];
    }
}

// ---------------- K3: per-mode complex channel mix.  Yf[b][o][ky][kx]
__global__ __launch_bounds__(256) void k3_mix(const float* __restrict__ xf_re,
                                              const float* __restrict__ xf_im,
                                              const float* __restrict__ w1r, const float* __restrict__ w1i,
                                              const float* __restrict__ w2r, const float* __restrict__ w2i,
                                              float* __restrict__ yf_re, float* __restrict__ yf_im) {
    __shared__ float xr_l[4 * 64 * 32];
    __shared__ float xi_l[4 * 64 * 32];
    int blk = blockIdx.x;          // ((ky*8 + oct)*2 + bh)
    int bh = blk & 1;
    int oct = (blk >> 1) & 7;
    int ky = blk >> 4;
    for (int idx = threadIdx.x; idx < 4 * 64 * 32; idx += 256) {
        int bb = idx >> 11;
        int i = (idx >> 5) & 63;
        int kx = idx & 31;
        size_t g = ((size_t)((bh * 4 + bb) * 64 + i) * 64 + ky) * 32 + kx;
        xr_l[idx] = xf_re[g];
        xi_l[idx] = xf_im[g];
    }
    __syncthreads();
    const float* wr = (ky < 32) ? w1r : w2r;
    const float* wi = (ky < 32) ? w1i : w2i;
    int kyl = ky & 31;
    int t = threadIdx.x;
    int kx = t & 31, oo = t >> 5;
    int o = oct * 8 + oo;
    float accr[4] = {0.f, 0.f, 0.f, 0.f};
    float acci[4] = {0.f, 0.f, 0.f, 0.f};
    for (int i = 0; i < 64; ++i) {
        size_t wbase = ((size_t)(i * 64 + o) * 32 + kyl) * 32 + kx;
        float wrv = wr[wbase];
        float wiv = wi[wbase];
#pragma unroll
        for (int bb = 0; bb < 4; ++bb) {
            float xr = xr_l[(bb * 64 + i) * 32 + kx];
            float xi = xi_l[(bb * 64 + i) * 32 + kx];
            accr[bb] += xr * wrv - xi * wiv;
            acci[bb] += xr * wiv + xi * wrv;
        }
    }
#pragma unroll
    for (int bb = 0; bb < 4; ++bb) {
        int b = bh * 4 + bb;
        size_t g = ((size_t)(b * 64 + o) * 64 + ky) * 32 + kx;
        yf_re[g] = accr[bb];
        yf_im[g] = acci[bb];
    }
}

// ---------------- K4: inverse DFT along H (only 64 nonzero rows).  Yh[bc][h][kx]
__global__ __launch_bounds__(256) void k4_idfth(const float* __restrict__ yf_re,
                                                const float* __restrict__ yf_im,
                                                float* __restrict__ yh_re,
                                                float* __restrict__ yh_im) {
    __shared__ float yr_l[2048];
    __shared__ float yi_l[2048];
    int blk = blockIdx.x;
    int bc = blk >> 2, hq = blk & 3;
    size_t base = (size_t)bc * 2048;
    for (int idx = threadIdx.x; idx < 512; idx += 256) {
        ((float4*)yr_l)[idx] = ((const float4*)(yf_re + base))[idx];
        ((float4*)yi_l)[idx] = ((const float4*)(yf_im + base))[idx];
    }
    __syncthreads();
    int t = threadIdx.x;
    int kx = t & 31, hgrp = t >> 5;
    int h0 = hq * 64 + hgrp * 8;
    float cdh[8], sdh[8], cc[8], ss[8], ar[8], ai[8];
#pragma unroll
    for (int hh = 0; hh < 8; ++hh) {
        sincosf(OMEGA * (float)(h0 + hh), &sdh[hh], &cdh[hh]);
        cc[hh] = 1.f; ss[hh] = 0.f; ar[hh] = 0.f; ai[hh] = 0.f;
    }
    for (int j = 0; j < 64; ++j) {
        if (j == 32) {
#pragma unroll
            for (int hh = 0; hh < 8; ++hh) ss[hh] = -ss[hh];
        }
        float yr = yr_l[j * 32 + kx], yi = yi_l[j * 32 + kx];
#pragma unroll
        for (int hh = 0; hh < 8; ++hh) {
            // (yr + i yi) * (c + i s)
            ar[hh] += yr * cc[hh] - yi * ss[hh];
            ai[hh] += yr * ss[hh] + yi * cc[hh];
            float c2 = cc[hh] * cdh[hh] - ss[hh] * sdh[hh];
            ss[hh] = ss[hh] * cdh[hh] + cc[hh] * sdh[hh];
            cc[hh] = c2;
        }
    }
    const float sc = 1.0f / 65536.0f;   // 1/(H*W) folded here
#pragma unroll
    for (int hh = 0; hh < 8; ++hh) {
        size_t g = ((size_t)bc * NH + h0 + hh) * NM + kx;
        yh_re[g] = ar[hh] * sc;
        yh_im[g] = ai[hh] * sc;
    }
}

// ---------------- K5: inverse real DFT along W + GN1 statistics.  y -> d_out
__global__ __launch_bounds__(128) void k5_irfftw(const float* __restrict__ yh_re,
                                                 const float* __restrict__ yh_im,
                                                 float* __restrict__ yout,
                                                 float* __restrict__ gn_acc) {
    __shared__ float zr_l[128 * 33];
    __shared__ float zi_l[128 * 33];
    __shared__ float rsum[2], rsq[2];
    int blk = blockIdx.x;
    int bc = blk >> 1, hhalf = blk & 1;
    size_t base = ((size_t)bc * NH + hhalf * 128) * NM;
    for (int idx = threadIdx.x; idx < 128 * 32; idx += 128) {
        int hl = idx >> 5, kx = idx & 31;
        zr_l[hl * 33 + kx] = yh_re[base + idx];
        zi_l[hl * 33 + kx] = yh_im[base + idx];
    }
    __syncthreads();
    int t = threadIdx.x;
    float zr[32], zi[32];
#pragma unroll
    for (int kx = 0; kx < 32; ++kx) {
        float m = (kx == 0) ? 1.f : 2.f;   // irfft doubling for kx>=1
        zr[kx] = zr_l[t * 33 + kx] * m;
        zi[kx] = zi_l[t * 33 + kx] * m;
    }
    int h = hhalf * 128 + t;
    float* orow = yout + (size_t)bc * NHW + (size_t)h * NW;
    float cw = 1.f, sw = 0.f;
    float cdw, sdw;
    sincosf(OMEGA, &sdw, &cdw);
    float sum = 0.f, sq = 0.f;
    for (int w4 = 0; w4 < 64; ++w4) {
        float res[4];
#pragma unroll
        for (int q = 0; q < 4; ++q) {
            float c = cw, s = sw;          // e^{+i*w*kx}, kx = 1
            float acc = zr[0];             // DC: Re only (pocketfft semantics)
#pragma unroll
            for (int kx = 1; kx < 32; ++kx) {
                acc += zr[kx] * c - zi[kx] * s;
                float c2 = c * cw - s * sw;
                s = s * cw + c * sw;
                c = c2;
            }
            res[q] = acc;
            sum += acc;
            sq += acc * acc;
            float c2 = cw * cdw - sw * sdw;  // advance w
            sw = sw * cdw + cw * sdw;
            cw = c2;
        }
        ((float4*)orow)[w4] = make_float4(res[0], res[1], res[2], res[3]);
    }
#pragma unroll
    for (int off = 32; off > 0; off >>= 1) {
        sum += __shfl_down(sum, off);
        sq += __shfl_down(sq, off);
    }
    int lane = t & 63, wv = t >> 6;
    if (lane == 0) { rsum[wv] = sum; rsq[wv] = sq; }
    __syncthreads();
    if (t == 0) {
        int b = bc >> 6;
        atomicAdd(&gn_acc[b * 4 + 0], rsum[0] + rsum[1]);
        atomicAdd(&gn_acc[b * 4 + 1], rsq[0] + rsq[1]);
    }
}

// ---------------- K6: GN1 + residual + gelu + MLP via SPLIT-BF16 MFMA + GN2 stats
// Precision: operands stored as (hi, lo) bf16 pairs, lo = bf16(f - f32(hi)).
// Each product uses 3 MFMAs: hi*hi + hi*lo + lo*hi -> ~2^-17 relative error
// (GN2 divides by sigma~0.064, a x15.6 amplification; plain bf16 gave 0.0625).
// RACE FIX (this round): __syncthreads() between the param/weight LDS staging
// and stage 1 — stage 1 reads nwl/nbl written only by wave 0; without the
// barrier, waves 1-3 can read them before they are written (probabilistic,
// explains the flaky line-490 failure of the previously-verified kernel and
// round 1's 0.883 absmax).
// LDS layout (byte offsets), phase-1 region aliased by fp32 out buffer:
//   vbuf_h @0      128 x 72 bf16 = 18432
//   vbuf_l @18432  128 x 72 bf16 = 18432
//   w1_h   @36864   32 x 72 bf16 = 4608
//   w1_l   @41472   32 x 72 bf16 = 4608
//   hbuf_h @46080  128 x 40 bf16 = 10240
//   hbuf_l @56320  128 x 40 bf16 = 10240
//   w2_h   @66560   64 x 40 bf16 = 5120
//   w2_l   @71680   64 x 40 bf16 = 5120
//   outbuf @0       64 x 132 f32 = 33792   (aliases vbuf_h/l; safe: sync before use)
//   params @76800  nw,nb(64ea) b1(32) b2(64) red(8) f32 = 928
// Total 77728 B -> 2 blocks/CU (8 waves/CU).
__global__ __launch_bounds__(256, 2) void k6_mlp(const float* __restrict__ x,
                                                 const float* __restrict__ norm1_w,
                                                 const float* __restrict__ norm1_b,
                                                 const float* __restrict__ mlp_w1,
                                                 const float* __restrict__ mlp_b1,
                                                 const float* __restrict__ mlp_w2,
                                                 const float* __restrict__ mlp_b2,
                                                 float* __restrict__ y,
                                                 float* __restrict__ gn_acc) {
    __shared__ __align__(16) unsigned char smem[77728];
    unsigned short* vbuf_h = (unsigned short*)smem;
    unsigned short* vbuf_l = (unsigned short*)(smem + 18432);
    unsigned short* w1_h   = (unsigned short*)(smem + 36864);
    unsigned short* w1_l   = (unsigned short*)(smem + 41472);
    unsigned short* hbuf_h = (unsigned short*)(smem + 46080);
    unsigned short* hbuf_l = (unsigned short*)(smem + 56320);
    unsigned short* w2_h   = (unsigned short*)(smem + 66560);
    unsigned short* w2_l   = (unsigned short*)(smem + 71680);
    float* outbuf = (float*)smem;                 // alias (phase 2)
    float* nwl = (float*)(smem + 76800);
    float* nbl = nwl + 64;
    float* b1l = nbl + 64;
    float* b2l = b1l + 32;
    float* red = b2l + 64;

    int t = threadIdx.x;
    int blk = blockIdx.x;
    int b = blk >> 9;                  // 512 blocks per sample
    int pixbase = (blk & 511) * 128;
    size_t bbase = (size_t)b * NC * NHW + pixbase;

    // --- load params first (so they land quickly), then weights (fp32 -> bf16 hi/lo)
    if (t < 64) { nwl[t] = norm1_w[t]; nbl[t] = norm1_b[t]; b2l[t] = mlp_b2[t]; }
    if (t >= 64 && t < 96) b1l[t - 64] = mlp_b1[t - 64];
    for (int idx = t; idx < 2048; idx += 256) {
        float wv1 = mlp_w1[idx];
        unsigned short h1 = f2bf(wv1);
        int r1 = (idx >> 6) * 72 + (idx & 63);
        w1_h[r1] = h1;
        w1_l[r1] = f2bf(wv1 - bf2f(h1));
        float wv2 = mlp_w2[idx];
        unsigned short h2 = f2bf(wv2);
        int r2 = (idx >> 5) * 40 + (idx & 31);
        w2_h[r2] = h2;
        w2_l[r2] = f2bf(wv2 - bf2f(h2));
    }
    __syncthreads();   // RACE FIX: nwl/nbl must be visible before stage 1 reads them

    // --- stage 1: v = gelu(gn1(y)*nw+nb + x), bf16 hi/lo into vbuf[pix][c]
    const float invN = 1.0f / (float)NPS;
    float m1 = gn_acc[b * 4 + 0] * invN;
    float var1 = gn_acc[b * 4 + 1] * invN - m1 * m1;
    float rs1 = rsqrtf(var1 + GN_EPS);
    {
        int p = t & 127;
        int c0 = (t >> 7) * 32;
        size_t base = bbase + (size_t)c0 * NHW + p;
#pragma unroll 8
        for (int ci = 0; ci < 32; ++ci) {
            float yv = y[base + (size_t)ci * NHW];
            float xv = x[base + (size_t)ci * NHW];
            int c = c0 + ci;
            float g = (yv - m1) * rs1 * nwl[c] + nbl[c] + xv;
            float vv = gelu_f(g);
            unsigned short vh = f2bf(vv);
            vbuf_h[p * 72 + c] = vh;
            vbuf_l[p * 72 + c] = f2bf(vv - bf2f(vh));
        }
    }
    __syncthreads();

    int lane = t & 63, wv = t >> 6;
    int lm = lane & 15, lg = lane >> 4;

    // --- layer 1 MFMA: h[128x32] = v[128x64] @ w1^T (3-term split), + b1, gelu
    floatx4 acc1[2][2] = {};
#pragma unroll
    for (int ks = 0; ks < 2; ++ks) {
        shortx8 ah[2], al[2], bh[2], bl[2];
#pragma unroll
        for (int mt = 0; mt < 2; ++mt) {
            int off = (wv * 32 + mt * 16 + lm) * 72 + lg * 8 + ks * 32;
            ah[mt] = *(const shortx8*)&vbuf_h[off];
            al[mt] = *(const shortx8*)&vbuf_l[off];
        }
#pragma unroll
        for (int nt = 0; nt < 2; ++nt) {
            int off = (nt * 16 + lm) * 72 + lg * 8 + ks * 32;
            bh[nt] = *(const shortx8*)&w1_h[off];
            bl[nt] = *(const shortx8*)&w1_l[off];
        }
#pragma unroll
        for (int mt = 0; mt < 2; ++mt)
#pragma unroll
            for (int nt = 0; nt < 2; ++nt) {
                acc1[mt][nt] = __builtin_amdgcn_mfma_f32_16x16x32_bf16(ah[mt], bh[nt], acc1[mt][nt], 0, 0, 0);
                acc1[mt][nt] = __builtin_amdgcn_mfma_f32_16x16x32_bf16(ah[mt], bl[nt], acc1[mt][nt], 0, 0, 0);
                acc1[mt][nt] = __builtin_amdgcn_mfma_f32_16x16x32_bf16(al[mt], bh[nt], acc1[mt][nt], 0, 0, 0);
            }
    }
#pragma unroll
    for (int mt = 0; mt < 2; ++mt)
#pragma unroll
        for (int nt = 0; nt < 2; ++nt) {
            float b1v = b1l[nt * 16 + lm];
#pragma unroll
            for (int r = 0; r < 4; ++r) {
                float hv = gelu_f(acc1[mt][nt][r] + b1v);
                unsigned short hh = f2bf(hv);
                int off = (wv * 32 + mt * 16 + lg * 4 + r) * 40 + nt * 16 + lm;
                hbuf_h[off] = hh;
                hbuf_l[off] = f2bf(hv - bf2f(hh));
            }
        }
    __syncthreads();

    // --- layer 2 MFMA: out[128x64] = h[128x32] @ w2^T (3-term split)
    floatx4 acc2[2][4] = {};
    {
        shortx8 ah2[2], al2[2], bh2[4], bl2[4];
#pragma unroll
        for (int mt = 0; mt < 2; ++mt) {
            int off = (wv * 32 + mt * 16 + lm) * 40 + lg * 8;
            ah2[mt] = *(const shortx8*)&hbuf_h[off];
            al2[mt] = *(const shortx8*)&hbuf_l[off];
        }
#pragma unroll
        for (int nt = 0; nt < 4; ++nt) {
            int off = (nt * 16 + lm) * 40 + lg * 8;
            bh2[nt] = *(const shortx8*)&w2_h[off];
            bl2[nt] = *(const shortx8*)&w2_l[off];
        }
#pragma unroll
        for (int mt = 0; mt < 2; ++mt)
#pragma unroll
            for (int nt = 0; nt < 4; ++nt) {
                acc2[mt][nt] = __builtin_amdgcn_mfma_f32_16x16x32_bf16(ah2[mt], bh2[nt], acc2[mt][nt], 0, 0, 0);
                acc2[mt][nt] = __builtin_amdgcn_mfma_f32_16x16x32_bf16(ah2[mt], bl2[nt], acc2[mt][nt], 0, 0, 0);
                acc2[mt][nt] = __builtin_amdgcn_mfma_f32_16x16x32_bf16(al2[mt], bh2[nt], acc2[mt][nt], 0, 0, 0);
            }
    }
    __syncthreads();   // all hbuf/w2buf reads done; outbuf may now clobber

    // --- write C-layout to fp32 outbuf[ch][pix] (+bias)
#pragma unroll
    for (int mt = 0; mt < 2; ++mt)
#pragma unroll
        for (int nt = 0; nt < 4; ++nt) {
            int ch = nt * 16 + lm;
            float b2v = b2l[ch];
#pragma unroll
            for (int r = 0; r < 4; ++r)
                outbuf[ch * 132 + wv * 32 + mt * 16 + lg * 4 + r] = acc2[mt][nt][r] + b2v;
        }
    __syncthreads();

    // --- coalesced global store + GN2 stats
    float sum = 0.f, sq = 0.f;
#pragma unroll
    for (int it = 0; it < 8; ++it) {
        int flat = it * 256 + t;
        int c = flat >> 5;
        int p4 = (flat & 31) * 4;
        float4 v = *(const float4*)&outbuf[c * 132 + p4];
        *(float4*)&y[bbase + (size_t)c * NHW + p4] = v;
        sum += v.x + v.y + v.z + v.w;
        sq += v.x * v.x + v.y * v.y + v.z * v.z + v.w * v.w;
    }
#pragma unroll
    for (int off = 32; off > 0; off >>= 1) {
        sum += __shfl_down(sum, off);
        sq += __shfl_down(sq, off);
    }
    if (lane == 0) { red[wv] = sum; red[4 + wv] = sq; }
    __syncthreads();
    if (t == 0) {
        atomicAdd(&gn_acc[b * 4 + 2], red[0] + red[1] + red[2] + red[3]);
        atomicAdd(&gn_acc[b * 4 + 3], red[4] + red[5] + red[6] + red[7]);
    }
}

// ---------------- K7: GN2 + FiLM + gelu(x) skip, elementwise, in-place
__global__ __launch_bounds__(256) void k7_final(const float* __restrict__ x,
                                                const float* __restrict__ gamma_bc,
                                                const float* __restrict__ beta_bc,
                                                const float* __restrict__ gn_acc,
                                                float* __restrict__ y) {
    size_t idx4 = (size_t)blockIdx.x * 256 + threadIdx.x;
    size_t base = idx4 * 4;
    int b = (int)(base >> 22);
    int c = (int)((base >> 16) & 63);
    const float invN = 1.0f / (float)NPS;
    float m2 = gn_acc[b * 4 + 2] * invN;
    float var2 = gn_acc[b * 4 + 3] * invN - m2 * m2;
    float rs2 = rsqrtf(var2 + GN_EPS);
    float g = gamma_bc[b * 64 + c];
    float be = beta_bc[b * 64 + c];
    float4 yv = ((float4*)y)[idx4];
    float4 xv = ((const float4*)x)[idx4];
    yv.x = g * ((yv.x - m2) * rs2) + be + gelu_f(xv.x);
    yv.y = g * ((yv.y - m2) * rs2) + be + gelu_f(xv.y);
    yv.z = g * ((yv.z - m2) * rs2) + be + gelu_f(xv.z);
    yv.w = g * ((yv.w - m2) * rs2) + be + gelu_f(xv.w);
    ((float4*)y)[idx4] = yv;
}

extern "C" void kernel_launch(void* const* d_in, const int* in_sizes, int n_in,
                              void* d_out, int out_size, void* d_ws, size_t ws_size,
                              hipStream_t stream) {
    (void)in_sizes; (void)n_in; (void)out_size; (void)ws_size;
    const float* x       = (const float*)d_in[0];
    const float* t_in    = (const float*)d_in[1];
    const float* w1r     = (const float*)d_in[2];
    const float* w1i     = (const float*)d_in[3];
    const float* w2r     = (const float*)d_in[4];
    const float* w2i     = (const float*)d_in[5];
    const float* norm1_w = (const float*)d_in[6];
    const float* norm1_b = (const float*)d_in[7];
    const float* mlp_w1  = (const float*)d_in[8];
    const float* mlp_b1  = (const float*)d_in[9];
    const float* mlp_w2  = (const float*)d_in[10];
    const float* mlp_b2  = (const float*)d_in[11];
    const float* gamma_w = (const float*)d_in[12];
    const float* gamma_b = (const float*)d_in[13];
    const float* beta_w  = (const float*)d_in[14];
    const float* beta_b  = (const float*)d_in[15];
    float* out = (float*)d_out;
    float* ws  = (float*)d_ws;

    float* gn_acc   = ws;            // 32
    float* gamma_bc = ws + 32;       // 512
    float* beta_bc  = ws + 544;      // 512
    float* xw_re    = ws + 2048;     // 4194304
    float* xw_im    = xw_re + 4194304;
    float* xf_re    = xw_im + 4194304;  // 1048576
    float* xf_im    = xf_re + 1048576;
    float* yf_re    = xf_im + 1048576;
    float* yf_im    = yf_re + 1048576;

    k0_init<<<dim3(1), dim3(256), 0, stream>>>(t_in, gamma_w, gamma_b, beta_w, beta_b,
                                               gn_acc, gamma_bc, beta_bc);
    k1_dftw<<<dim3(4096), dim3(128), 0, stream>>>(x, xw_re, xw_im);
    k2_dfth<<<dim3(512), dim3(256), 0, stream>>>(xw_re, xw_im, xf_re, xf_im);
    k3_mix<<<dim3(1024), dim3(256), 0, stream>>>(xf_re, xf_im, w1r, w1i, w2r, w2i,
                                                 yf_re, yf_im);
    k4_idfth<<<dim3(2048), dim3(256), 0, stream>>>(yf_re, yf_im, xw_re, xw_im);
    k5_irfftw<<<dim3(1024), dim3(128), 0, stream>>>(xw_re, xw_im, out, gn_acc);
    k6_mlp<<<dim3(4096), dim3(256), 0, stream>>>(x, norm1_w, norm1_b, mlp_w1, mlp_b1,
                                                 mlp_w2, mlp_b2, out, gn_acc);
    k7_final<<<dim3(32768), dim3(256), 0, stream>>>(x, gamma_bc, beta_bc, gn_acc, out);
}

// Round 3
// 727.326 us; speedup vs baseline: 1.2291x; 1.2291x over previous
//
#include <hip/hip_runtime.h>
#include <math.h>

#define NB 8
#define NC 64
#define NH 256
#define NW 256
#define NHW 65536
#define NM 32
#define NPS 4194304   // C*H*W per sample
#define GN_EPS 1e-5f
#define OMEGA 0.0245436926061703f  // 2*pi/256

typedef short shortx8 __attribute__((ext_vector_type(8)));
typedef float floatx4 __attribute__((ext_vector_type(4)));

__device__ __forceinline__ float gelu_f(float v) {
    return 0.5f * v * (1.0f + erff(v * 0.7071067811865475f));
}

__device__ __forceinline__ unsigned short f2bf(float f) {
    unsigned u = __builtin_bit_cast(unsigned, f);
    u = (u + 0x7fffu + ((u >> 16) & 1u)) >> 16;
    return (unsigned short)u;
}

__device__ __forceinline__ float bf2f(unsigned short u) {
    return __builtin_bit_cast(float, ((unsigned)u) << 16);
}

// ---------------- K0: zero GN accumulators, compute FiLM gamma/beta per (b,c)
__global__ void k0_init(const float* __restrict__ t_in,
                        const float* __restrict__ gamma_w, const float* __restrict__ gamma_b,
                        const float* __restrict__ beta_w, const float* __restrict__ beta_b,
                        float* __restrict__ gn_acc, float* __restrict__ gamma_bc,
                        float* __restrict__ beta_bc) {
    int t = threadIdx.x;
    if (t < 32) gn_acc[t] = 0.f;
    for (int idx = t; idx < NB * NC; idx += 256) {
        int b = idx >> 6, o = idx & 63;
        float g = gamma_b[o], be = beta_b[o];
        for (int c = 0; c < NC; ++c) {
            float tv = t_in[b * NC + c];
            g += gamma_w[o * NC + c] * tv;
            be += beta_w[o * NC + c] * tv;
        }
        gamma_bc[idx] = g;
        beta_bc[idx] = be;
    }
}

// ---------------- KT: precompute DFT twiddles as bf16 hi/lo pairs
// t1 (for K1, B^T layout [n=0..63][w=0..255]):
//   n<32:  cos(omega*n*w)     (re rows)
//   n>=32: -sin(omega*(n-32)*w)  (im rows; ai = -sum x sin)
// u (for K5, B^T layout [w=0..255][k=0..63]), irfft doubling m folded in:
//   k<32:  m_k*cos(omega*k*w),  m_0=1, m_k=2
//   k>=32: -m_k*sin(omega*(k-32)*w)   (k=32 -> 0: DC imag dropped)
__global__ __launch_bounds__(256) void k_tw(unsigned short* __restrict__ t1h,
                                            unsigned short* __restrict__ t1l,
                                            unsigned short* __restrict__ uh,
                                            unsigned short* __restrict__ ul) {
    int idx = blockIdx.x * 256 + threadIdx.x;
    if (idx >= 16384) return;
    {
        int n = idx >> 8, w = idx & 255;
        float ph = OMEGA * (float)(((n & 31) * w) & 255);  // exact phase mod 2*pi
        float s, c;
        sincosf(ph, &s, &c);
        float v = (n < 32) ? c : -s;
        unsigned short h = f2bf(v);
        t1h[idx] = h;
        t1l[idx] = f2bf(v - bf2f(h));
    }
    {
        int w = idx >> 6, k = idx & 63;
        int k31 = k & 31;
        float m = (k31 == 0) ? 1.f : 2.f;
        float ph = OMEGA * (float)((k31 * w) & 255);
        float s, c;
        sincosf(ph, &s, &c);
        float v = (k < 32) ? m * c : -m * s;
        unsigned short h = f2bf(v);
        uh[idx] = h;
        ul[idx] = f2bf(v - bf2f(h));
    }
}

// ---------------- K1: real DFT along W via split-bf16 MFMA GEMM.
// Xw[row=bc*256+h][n] = sum_w x[row][w] * T[n][w],  n<32 -> re[kx=n], n>=32 -> im[kx=n-32].
// Block: 256 threads (4 waves), 128 rows, K=256 in 4 steps of 64. N=64.
// A staged in LDS (pitch 72 bf16 vs 64 to break bank conflicts), hi/lo pair.
// B (twiddle) fragments loaded directly from global (64KB hi+lo, L2-resident).
__global__ __launch_bounds__(256, 4) void k1_dftw(const float* __restrict__ x,
                                                  const unsigned short* __restrict__ t1h,
                                                  const unsigned short* __restrict__ t1l,
                                                  float* __restrict__ xw_re,
                                                  float* __restrict__ xw_im) {
    __shared__ unsigned short a_h[128 * 72];
    __shared__ unsigned short a_l[128 * 72];
    int blk = blockIdx.x;          // 1024 = 512 bc * 2 row-halves
    int bc = blk >> 1;
    int h0 = (blk & 1) * 128;
    const float* src = x + (size_t)bc * NHW + (size_t)h0 * NW;
    int t = threadIdx.x;
    int lane = t & 63, wv = t >> 6, lm = lane & 15, lg = lane >> 4;

    floatx4 acc[2][4] = {};
#pragma unroll
    for (int ks = 0; ks < 4; ++ks) {
        if (ks) __syncthreads();       // prior ds_reads done before overwrite
        // stage A chunk: 128 rows x 64 cols (f32 -> bf16 hi/lo)
        for (int i = t; i < 2048; i += 256) {
            int r = i >> 4;
            int c4 = (i & 15) << 2;
            float4 v = *(const float4*)&src[(size_t)r * NW + (ks << 6) + c4];
            int off = r * 72 + c4;
            ushort4 h4, l4;
            h4.x = f2bf(v.x); l4.x = f2bf(v.x - bf2f(h4.x));
            h4.y = f2bf(v.y); l4.y = f2bf(v.y - bf2f(h4.y));
            h4.z = f2bf(v.z); l4.z = f2bf(v.z - bf2f(h4.z));
            h4.w = f2bf(v.w); l4.w = f2bf(v.w - bf2f(h4.w));
            *(ushort4*)&a_h[off] = h4;
            *(ushort4*)&a_l[off] = l4;
        }
        __syncthreads();
#pragma unroll
        for (int kk = 0; kk < 2; ++kk) {
            shortx8 ah[2], al[2], bh[4], bl[4];
#pragma unroll
            for (int mt = 0; mt < 2; ++mt) {
                int off = (wv * 32 + mt * 16 + lm) * 72 + kk * 32 + lg * 8;
                ah[mt] = *(const shortx8*)&a_h[off];
                al[mt] = *(const shortx8*)&a_l[off];
            }
#pragma unroll
            for (int nt = 0; nt < 4; ++nt) {
                int off = (nt * 16 + lm) * 256 + ks * 64 + kk * 32 + lg * 8;
                bh[nt] = *(const shortx8*)&t1h[off];
                bl[nt] = *(const shortx8*)&t1l[off];
            }
#pragma unroll
            for (int mt = 0; mt < 2; ++mt)
#pragma unroll
                for (int nt = 0; nt < 4; ++nt) {
                    acc[mt][nt] = __builtin_amdgcn_mfma_f32_16x16x32_bf16(ah[mt], bh[nt], acc[mt][nt], 0, 0, 0);
                    acc[mt][nt] = __builtin_amdgcn_mfma_f32_16x16x32_bf16(ah[mt], bl[nt], acc[mt][nt], 0, 0, 0);
                    acc[mt][nt] = __builtin_amdgcn_mfma_f32_16x16x32_bf16(al[mt], bh[nt], acc[mt][nt], 0, 0, 0);
                }
        }
    }
    size_t rowg = (size_t)bc * NH + h0;
#pragma unroll
    for (int mt = 0; mt < 2; ++mt)
#pragma unroll
        for (int nt = 0; nt < 4; ++nt) {
            int n = nt * 16 + lm;
            float* dst = (n < 32) ? xw_re : xw_im;
            int kx = n & 31;
#pragma unroll
            for (int r = 0; r < 4; ++r) {
                int row = wv * 32 + mt * 16 + lg * 4 + r;
                dst[(rowg + row) * NM + kx] = acc[mt][nt][r];
            }
        }
}

// ---------------- K2: complex DFT along H at kept rows.  Xf[bc][j64][kx]
__global__ __launch_bounds__(256) void k2_dfth(const float* __restrict__ xw_re,
                                               const float* __restrict__ xw_im,
                                               float* __restrict__ xf_re,
                                               float* __restrict__ xf_im) {
    __shared__ float xr_l[NH * NM];
    __shared__ float xi_l[NH * NM];
    int bc = blockIdx.x;
    size_t base = (size_t)bc * NH * NM;
    for (int idx = threadIdx.x; idx < NH * NM / 4; idx += 256) {
        ((float4*)xr_l)[idx] = ((const float4*)(xw_re + base))[idx];
        ((float4*)xi_l)[idx] = ((const float4*)(xw_im + base))[idx];
    }
    __syncthreads();
    int t = threadIdx.x;
    int kx = t & 31, jgrp = t >> 5;
    float cd[8], sd[8], cc[8], ss[8], ar[8], ai[8];
#pragma unroll
    for (int jj = 0; jj < 8; ++jj) {
        int j = jgrp * 8 + jj;
        int f = (j < 32) ? j : 192 + j;     // actual row frequency
        sincosf(OMEGA * (float)f, &sd[jj], &cd[jj]);
        cc[jj] = 1.f; ss[jj] = 0.f; ar[jj] = 0.f; ai[jj] = 0.f;
    }
    for (int h = 0; h < 256; ++h) {
        float xr = xr_l[h * NM + kx], xi = xi_l[h * NM + kx];
#pragma unroll
        for (int jj = 0; jj < 8; ++jj) {
            // (xr + i xi) * (c - i s)
            ar[jj] += xr * cc[jj] + xi * ss[jj];
            ai[jj] += xi * cc[jj] - xr * ss[jj];
            float c2 = cc[jj] * cd[jj] - ss[jj] * sd[jj];
            ss[jj] = ss[jj] * cd[jj] + cc[jj] * sd[jj];
            cc[jj] = c2;
        }
    }
    size_t ob = (size_t)bc * 2048;
#pragma unroll
    for (int jj = 0; jj < 8; ++jj) {
        int j = jgrp * 8 + jj;
        xf_re[ob + j * 32 + kx] = ar[jj];
        xf_im[ob + j * 32 + kx] = ai[jj];
    }
}

// ---------------- K3: per-mode complex channel mix.  Yf[b][o][ky][kx]
__global__ __launch_bounds__(256) void k3_mix(const float* __restrict__ xf_re,
                                              const float* __restrict__ xf_im,
                                              const float* __restrict__ w1r, const float* __restrict__ w1i,
                                              const float* __restrict__ w2r, const float* __restrict__ w2i,
                                              float* __restrict__ yf_re, float* __restrict__ yf_im) {
    __shared__ float xr_l[4 * 64 * 32];
    __shared__ float xi_l[4 * 64 * 32];
    int blk = blockIdx.x;          // ((ky*8 + oct)*2 + bh)
    int bh = blk & 1;
    int oct = (blk >> 1) & 7;
    int ky = blk >> 4;
    for (int idx = threadIdx.x; idx < 4 * 64 * 32; idx += 256) {
        int bb = idx >> 11;
        int i = (idx >> 5) & 63;
        int kx = idx & 31;
        size_t g = ((size_t)((bh * 4 + bb) * 64 + i) * 64 + ky) * 32 + kx;
        xr_l[idx] = xf_re[g];
        xi_l[idx] = xf_im[g];
    }
    __syncthreads();
    const float* wr = (ky < 32) ? w1r : w2r;
    const float* wi = (ky < 32) ? w1i : w2i;
    int kyl = ky & 31;
    int t = threadIdx.x;
    int kx = t & 31, oo = t >> 5;
    int o = oct * 8 + oo;
    float accr[4] = {0.f, 0.f, 0.f, 0.f};
    float acci[4] = {0.f, 0.f, 0.f, 0.f};
    for (int i = 0; i < 64; ++i) {
        size_t wbase = ((size_t)(i * 64 + o) * 32 + kyl) * 32 + kx;
        float wrv = wr[wbase];
        float wiv = wi[wbase];
#pragma unroll
        for (int bb = 0; bb < 4; ++bb) {
            float xr = xr_l[(bb * 64 + i) * 32 + kx];
            float xi = xi_l[(bb * 64 + i) * 32 + kx];
            accr[bb] += xr * wrv - xi * wiv;
            acci[bb] += xr * wiv + xi * wrv;
        }
    }
#pragma unroll
    for (int bb = 0; bb < 4; ++bb) {
        int b = bh * 4 + bb;
        size_t g = ((size_t)(b * 64 + o) * 64 + ky) * 32 + kx;
        yf_re[g] = accr[bb];
        yf_im[g] = acci[bb];
    }
}

// ---------------- K4: inverse DFT along H (only 64 nonzero rows).  Yh[bc][h][kx]
__global__ __launch_bounds__(256) void k4_idfth(const float* __restrict__ yf_re,
                                                const float* __restrict__ yf_im,
                                                float* __restrict__ yh_re,
                                                float* __restrict__ yh_im) {
    __shared__ float yr_l[2048];
    __shared__ float yi_l[2048];
    int blk = blockIdx.x;
    int bc = blk >> 2, hq = blk & 3;
    size_t base = (size_t)bc * 2048;
    for (int idx = threadIdx.x; idx < 512; idx += 256) {
        ((float4*)yr_l)[idx] = ((const float4*)(yf_re + base))[idx];
        ((float4*)yi_l)[idx] = ((const float4*)(yf_im + base))[idx];
    }
    __syncthreads();
    int t = threadIdx.x;
    int kx = t & 31, hgrp = t >> 5;
    int h0 = hq * 64 + hgrp * 8;
    float cdh[8], sdh[8], cc[8], ss[8], ar[8], ai[8];
#pragma unroll
    for (int hh = 0; hh < 8; ++hh) {
        sincosf(OMEGA * (float)(h0 + hh), &sdh[hh], &cdh[hh]);
        cc[hh] = 1.f; ss[hh] = 0.f; ar[hh] = 0.f; ai[hh] = 0.f;
    }
    for (int j = 0; j < 64; ++j) {
        if (j == 32) {
#pragma unroll
            for (int hh = 0; hh < 8; ++hh) ss[hh] = -ss[hh];
        }
        float yr = yr_l[j * 32 + kx], yi = yi_l[j * 32 + kx];
#pragma unroll
        for (int hh = 0; hh < 8; ++hh) {
            // (yr + i yi) * (c + i s)
            ar[hh] += yr * cc[hh] - yi * ss[hh];
            ai[hh] += yr * ss[hh] + yi * cc[hh];
            float c2 = cc[hh] * cdh[hh] - ss[hh] * sdh[hh];
            ss[hh] = ss[hh] * cdh[hh] + cc[hh] * sdh[hh];
            cc[hh] = c2;
        }
    }
    const float sc = 1.0f / 65536.0f;   // 1/(H*W) folded here
#pragma unroll
    for (int hh = 0; hh < 8; ++hh) {
        size_t g = ((size_t)bc * NH + h0 + hh) * NM + kx;
        yh_re[g] = ar[hh] * sc;
        yh_im[g] = ai[hh] * sc;
    }
}

// ---------------- K5: inverse real DFT along W via split-bf16 MFMA + GN1 stats.
// y[row][w] = sum_k Z[row][k] * U[w][k], Z = [zr(32) | zi(32)], doubling folded in U.
// Block: 256 threads (4 waves), 128 rows, K=64 (single step), N=256.
__global__ __launch_bounds__(256, 2) void k5_irfftw(const float* __restrict__ yh_re,
                                                    const float* __restrict__ yh_im,
                                                    const unsigned short* __restrict__ uh,
                                                    const unsigned short* __restrict__ ul,
                                                    float* __restrict__ yout,
                                                    float* __restrict__ gn_acc) {
    __shared__ unsigned short a_h[128 * 72];
    __shared__ unsigned short a_l[128 * 72];
    __shared__ float red[8];
    int blk = blockIdx.x;          // 1024 blocks of 128 rows
    size_t row0 = (size_t)blk * 128;
    int t = threadIdx.x;

    // stage Z: 128 rows x (32 re | 32 im) -> bf16 hi/lo, pitch 72
    for (int i = t; i < 1024; i += 256) {
        int r = i >> 3;
        int c4 = (i & 7) << 2;
        float4 vr = *(const float4*)&yh_re[(row0 + r) * NM + c4];
        float4 vi = *(const float4*)&yh_im[(row0 + r) * NM + c4];
        int offr = r * 72 + c4;
        ushort4 h4, l4;
        h4.x = f2bf(vr.x); l4.x = f2bf(vr.x - bf2f(h4.x));
        h4.y = f2bf(vr.y); l4.y = f2bf(vr.y - bf2f(h4.y));
        h4.z = f2bf(vr.z); l4.z = f2bf(vr.z - bf2f(h4.z));
        h4.w = f2bf(vr.w); l4.w = f2bf(vr.w - bf2f(h4.w));
        *(ushort4*)&a_h[offr] = h4;
        *(ushort4*)&a_l[offr] = l4;
        h4.x = f2bf(vi.x); l4.x = f2bf(vi.x - bf2f(h4.x));
        h4.y = f2bf(vi.y); l4.y = f2bf(vi.y - bf2f(h4.y));
        h4.z = f2bf(vi.z); l4.z = f2bf(vi.z - bf2f(h4.z));
        h4.w = f2bf(vi.w); l4.w = f2bf(vi.w - bf2f(h4.w));
        *(ushort4*)&a_h[offr + 32] = h4;
        *(ushort4*)&a_l[offr + 32] = l4;
    }
    __syncthreads();

    int lane = t & 63, wv = t >> 6, lm = lane & 15, lg = lane >> 4;
    floatx4 acc[2][16] = {};
#pragma unroll
    for (int kk = 0; kk < 2; ++kk) {
        shortx8 ah[2], al[2];
#pragma unroll
        for (int mt = 0; mt < 2; ++mt) {
            int off = (wv * 32 + mt * 16 + lm) * 72 + kk * 32 + lg * 8;
            ah[mt] = *(const shortx8*)&a_h[off];
            al[mt] = *(const shortx8*)&a_l[off];
        }
#pragma unroll
        for (int nt = 0; nt < 16; ++nt) {
            int w = nt * 16 + lm;
            shortx8 bh = *(const shortx8*)&uh[w * 64 + kk * 32 + lg * 8];
            shortx8 bl = *(const shortx8*)&ul[w * 64 + kk * 32 + lg * 8];
#pragma unroll
            for (int mt = 0; mt < 2; ++mt) {
                acc[mt][nt] = __builtin_amdgcn_mfma_f32_16x16x32_bf16(ah[mt], bh, acc[mt][nt], 0, 0, 0);
                acc[mt][nt] = __builtin_amdgcn_mfma_f32_16x16x32_bf16(ah[mt], bl, acc[mt][nt], 0, 0, 0);
                acc[mt][nt] = __builtin_amdgcn_mfma_f32_16x16x32_bf16(al[mt], bh, acc[mt][nt], 0, 0, 0);
            }
        }
    }

    // store + GN1 stats
    float sum = 0.f, sq = 0.f;
#pragma unroll
    for (int mt = 0; mt < 2; ++mt)
#pragma unroll
        for (int nt = 0; nt < 16; ++nt) {
            int w = nt * 16 + lm;
#pragma unroll
            for (int r = 0; r < 4; ++r) {
                int row = wv * 32 + mt * 16 + lg * 4 + r;
                float v = acc[mt][nt][r];
                yout[(row0 + row) * NW + w] = v;
                sum += v;
                sq += v * v;
            }
        }
#pragma unroll
    for (int off = 32; off > 0; off >>= 1) {
        sum += __shfl_down(sum, off);
        sq += __shfl_down(sq, off);
    }
    if (lane == 0) { red[wv] = sum; red[4 + wv] = sq; }
    __syncthreads();
    if (t == 0) {
        int b = blk >> 7;    // 128 blocks (16384 rows) per sample
        atomicAdd(&gn_acc[b * 4 + 0], red[0] + red[1] + red[2] + red[3]);
        atomicAdd(&gn_acc[b * 4 + 1], red[4] + red[5] + red[6] + red[7]);
    }
}

// ---------------- K6: GN1 + residual + gelu + MLP via SPLIT-BF16 MFMA + GN2 stats
__global__ __launch_bounds__(256, 2) void k6_mlp(const float* __restrict__ x,
                                                 const float* __restrict__ norm1_w,
                                                 const float* __restrict__ norm1_b,
                                                 const float* __restrict__ mlp_w1,
                                                 const float* __restrict__ mlp_b1,
                                                 const float* __restrict__ mlp_w2,
                                                 const float* __restrict__ mlp_b2,
                                                 float* __restrict__ y,
                                                 float* __restrict__ gn_acc) {
    __shared__ __align__(16) unsigned char smem[77728];
    unsigned short* vbuf_h = (unsigned short*)smem;
    unsigned short* vbuf_l = (unsigned short*)(smem + 18432);
    unsigned short* w1_h   = (unsigned short*)(smem + 36864);
    unsigned short* w1_l   = (unsigned short*)(smem + 41472);
    unsigned short* hbuf_h = (unsigned short*)(smem + 46080);
    unsigned short* hbuf_l = (unsigned short*)(smem + 56320);
    unsigned short* w2_h   = (unsigned short*)(smem + 66560);
    unsigned short* w2_l   = (unsigned short*)(smem + 71680);
    float* outbuf = (float*)smem;                 // alias (phase 2)
    float* nwl = (float*)(smem + 76800);
    float* nbl = nwl + 64;
    float* b1l = nbl + 64;
    float* b2l = b1l + 32;
    float* red = b2l + 64;

    int t = threadIdx.x;
    int blk = blockIdx.x;
    int b = blk >> 9;                  // 512 blocks per sample
    int pixbase = (blk & 511) * 128;
    size_t bbase = (size_t)b * NC * NHW + pixbase;

    if (t < 64) { nwl[t] = norm1_w[t]; nbl[t] = norm1_b[t]; b2l[t] = mlp_b2[t]; }
    if (t >= 64 && t < 96) b1l[t - 64] = mlp_b1[t - 64];
    for (int idx = t; idx < 2048; idx += 256) {
        float wv1 = mlp_w1[idx];
        unsigned short h1 = f2bf(wv1);
        int r1 = (idx >> 6) * 72 + (idx & 63);
        w1_h[r1] = h1;
        w1_l[r1] = f2bf(wv1 - bf2f(h1));
        float wv2 = mlp_w2[idx];
        unsigned short h2 = f2bf(wv2);
        int r2 = (idx >> 5) * 40 + (idx & 31);
        w2_h[r2] = h2;
        w2_l[r2] = f2bf(wv2 - bf2f(h2));
    }
    __syncthreads();   // RACE FIX: nwl/nbl visible before stage 1 reads them

    const float invN = 1.0f / (float)NPS;
    float m1 = gn_acc[b * 4 + 0] * invN;
    float var1 = gn_acc[b * 4 + 1] * invN - m1 * m1;
    float rs1 = rsqrtf(var1 + GN_EPS);
    {
        int p = t & 127;
        int c0 = (t >> 7) * 32;
        size_t base = bbase + (size_t)c0 * NHW + p;
#pragma unroll 8
        for (int ci = 0; ci < 32; ++ci) {
            float yv = y[base + (size_t)ci * NHW];
            float xv = x[base + (size_t)ci * NHW];
            int c = c0 + ci;
            float g = (yv - m1) * rs1 * nwl[c] + nbl[c] + xv;
            float vv = gelu_f(g);
            unsigned short vh = f2bf(vv);
            vbuf_h[p * 72 + c] = vh;
            vbuf_l[p * 72 + c] = f2bf(vv - bf2f(vh));
        }
    }
    __syncthreads();

    int lane = t & 63, wv = t >> 6;
    int lm = lane & 15, lg = lane >> 4;

    floatx4 acc1[2][2] = {};
#pragma unroll
    for (int ks = 0; ks < 2; ++ks) {
        shortx8 ah[2], al[2], bh[2], bl[2];
#pragma unroll
        for (int mt = 0; mt < 2; ++mt) {
            int off = (wv * 32 + mt * 16 + lm) * 72 + lg * 8 + ks * 32;
            ah[mt] = *(const shortx8*)&vbuf_h[off];
            al[mt] = *(const shortx8*)&vbuf_l[off];
        }
#pragma unroll
        for (int nt = 0; nt < 2; ++nt) {
            int off = (nt * 16 + lm) * 72 + lg * 8 + ks * 32;
            bh[nt] = *(const shortx8*)&w1_h[off];
            bl[nt] = *(const shortx8*)&w1_l[off];
        }
#pragma unroll
        for (int mt = 0; mt < 2; ++mt)
#pragma unroll
            for (int nt = 0; nt < 2; ++nt) {
                acc1[mt][nt] = __builtin_amdgcn_mfma_f32_16x16x32_bf16(ah[mt], bh[nt], acc1[mt][nt], 0, 0, 0);
                acc1[mt][nt] = __builtin_amdgcn_mfma_f32_16x16x32_bf16(ah[mt], bl[nt], acc1[mt][nt], 0, 0, 0);
                acc1[mt][nt] = __builtin_amdgcn_mfma_f32_16x16x32_bf16(al[mt], bh[nt], acc1[mt][nt], 0, 0, 0);
            }
    }
#pragma unroll
    for (int mt = 0; mt < 2; ++mt)
#pragma unroll
        for (int nt = 0; nt < 2; ++nt) {
            float b1v = b1l[nt * 16 + lm];
#pragma unroll
            for (int r = 0; r < 4; ++r) {
                float hv = gelu_f(acc1[mt][nt][r] + b1v);
                unsigned short hh = f2bf(hv);
                int off = (wv * 32 + mt * 16 + lg * 4 + r) * 40 + nt * 16 + lm;
                hbuf_h[off] = hh;
                hbuf_l[off] = f2bf(hv - bf2f(hh));
            }
        }
    __syncthreads();

    floatx4 acc2[2][4] = {};
    {
        shortx8 ah2[2], al2[2], bh2[4], bl2[4];
#pragma unroll
        for (int mt = 0; mt < 2; ++mt) {
            int off = (wv * 32 + mt * 16 + lm) * 40 + lg * 8;
            ah2[mt] = *(const shortx8*)&hbuf_h[off];
            al2[mt] = *(const shortx8*)&hbuf_l[off];
        }
#pragma unroll
        for (int nt = 0; nt < 4; ++nt) {
            int off = (nt * 16 + lm) * 40 + lg * 8;
            bh2[nt] = *(const shortx8*)&w2_h[off];
            bl2[nt] = *(const shortx8*)&w2_l[off];
        }
#pragma unroll
        for (int mt = 0; mt < 2; ++mt)
#pragma unroll
            for (int nt = 0; nt < 4; ++nt) {
                acc2[mt][nt] = __builtin_amdgcn_mfma_f32_16x16x32_bf16(ah2[mt], bh2[nt], acc2[mt][nt], 0, 0, 0);
                acc2[mt][nt] = __builtin_amdgcn_mfma_f32_16x16x32_bf16(ah2[mt], bl2[nt], acc2[mt][nt], 0, 0, 0);
                acc2[mt][nt] = __builtin_amdgcn_mfma_f32_16x16x32_bf16(al2[mt], bh2[nt], acc2[mt][nt], 0, 0, 0);
            }
    }
    __syncthreads();   // all hbuf/w2buf reads done; outbuf may now clobber

#pragma unroll
    for (int mt = 0; mt < 2; ++mt)
#pragma unroll
        for (int nt = 0; nt < 4; ++nt) {
            int ch = nt * 16 + lm;
            float b2v = b2l[ch];
#pragma unroll
            for (int r = 0; r < 4; ++r)
                outbuf[ch * 132 + wv * 32 + mt * 16 + lg * 4 + r] = acc2[mt][nt][r] + b2v;
        }
    __syncthreads();

    float sum = 0.f, sq = 0.f;
#pragma unroll
    for (int it = 0; it < 8; ++it) {
        int flat = it * 256 + t;
        int c = flat >> 5;
        int p4 = (flat & 31) * 4;
        float4 v = *(const float4*)&outbuf[c * 132 + p4];
        *(float4*)&y[bbase + (size_t)c * NHW + p4] = v;
        sum += v.x + v.y + v.z + v.w;
        sq += v.x * v.x + v.y * v.y + v.z * v.z + v.w * v.w;
    }
#pragma unroll
    for (int off = 32; off > 0; off >>= 1) {
        sum += __shfl_down(sum, off);
        sq += __shfl_down(sq, off);
    }
    if (lane == 0) { red[wv] = sum; red[4 + wv] = sq; }
    __syncthreads();
    if (t == 0) {
        atomicAdd(&gn_acc[b * 4 + 2], red[0] + red[1] + red[2] + red[3]);
        atomicAdd(&gn_acc[b * 4 + 3], red[4] + red[5] + red[6] + red[7]);
    }
}

// ---------------- K7: GN2 + FiLM + gelu(x) skip, elementwise, in-place
__global__ __launch_bounds__(256) void k7_final(const float* __restrict__ x,
                                                const float* __restrict__ gamma_bc,
                                                const float* __restrict__ beta_bc,
                                                const float* __restrict__ gn_acc,
                                                float* __restrict__ y) {
    size_t idx4 = (size_t)blockIdx.x * 256 + threadIdx.x;
    size_t base = idx4 * 4;
    int b = (int)(base >> 22);
    int c = (int)((base >> 16) & 63);
    const float invN = 1.0f / (float)NPS;
    float m2 = gn_acc[b * 4 + 2] * invN;
    float var2 = gn_acc[b * 4 + 3] * invN - m2 * m2;
    float rs2 = rsqrtf(var2 + GN_EPS);
    float g = gamma_bc[b * 64 + c];
    float be = beta_bc[b * 64 + c];
    float4 yv = ((float4*)y)[idx4];
    float4 xv = ((const float4*)x)[idx4];
    yv.x = g * ((yv.x - m2) * rs2) + be + gelu_f(xv.x);
    yv.y = g * ((yv.y - m2) * rs2) + be + gelu_f(xv.y);
    yv.z = g * ((yv.z - m2) * rs2) + be + gelu_f(xv.z);
    yv.w = g * ((yv.w - m2) * rs2) + be + gelu_f(xv.w);
    ((float4*)y)[idx4] = yv;
}

extern "C" void kernel_launch(void* const* d_in, const int* in_sizes, int n_in,
                              void* d_out, int out_size, void* d_ws, size_t ws_size,
                              hipStream_t stream) {
    (void)in_sizes; (void)n_in; (void)out_size; (void)ws_size;
    const float* x       = (const float*)d_in[0];
    const float* t_in    = (const float*)d_in[1];
    const float* w1r     = (const float*)d_in[2];
    const float* w1i     = (const float*)d_in[3];
    const float* w2r     = (const float*)d_in[4];
    const float* w2i     = (const float*)d_in[5];
    const float* norm1_w = (const float*)d_in[6];
    const float* norm1_b = (const float*)d_in[7];
    const float* mlp_w1  = (const float*)d_in[8];
    const float* mlp_b1  = (const float*)d_in[9];
    const float* mlp_w2  = (const float*)d_in[10];
    const float* mlp_b2  = (const float*)d_in[11];
    const float* gamma_w = (const float*)d_in[12];
    const float* gamma_b = (const float*)d_in[13];
    const float* beta_w  = (const float*)d_in[14];
    const float* beta_b  = (const float*)d_in[15];
    float* out = (float*)d_out;
    float* ws  = (float*)d_ws;

    float* gn_acc   = ws;            // 32
    float* gamma_bc = ws + 32;       // 512
    float* beta_bc  = ws + 544;      // 512
    float* xw_re    = ws + 2048;     // 4194304
    float* xw_im    = xw_re + 4194304;
    float* xf_re    = xw_im + 4194304;  // 1048576
    float* xf_im    = xf_re + 1048576;
    float* yf_re    = xf_im + 1048576;
    float* yf_im    = yf_re + 1048576;
    unsigned short* t1h = (unsigned short*)(yf_im + 1048576);  // 16384 each
    unsigned short* t1l = t1h + 16384;
    unsigned short* uh  = t1l + 16384;
    unsigned short* ul  = uh + 16384;

    k_tw<<<dim3(64), dim3(256), 0, stream>>>(t1h, t1l, uh, ul);
    k0_init<<<dim3(1), dim3(256), 0, stream>>>(t_in, gamma_w, gamma_b, beta_w, beta_b,
                                               gn_acc, gamma_bc, beta_bc);
    k1_dftw<<<dim3(1024), dim3(256), 0, stream>>>(x, t1h, t1l, xw_re, xw_im);
    k2_dfth<<<dim3(512), dim3(256), 0, stream>>>(xw_re, xw_im, xf_re, xf_im);
    k3_mix<<<dim3(1024), dim3(256), 0, stream>>>(xf_re, xf_im, w1r, w1i, w2r, w2i,
                                                 yf_re, yf_im);
    k4_idfth<<<dim3(2048), dim3(256), 0, stream>>>(yf_re, yf_im, xw_re, xw_im);
    k5_irfftw<<<dim3(1024), dim3(256), 0, stream>>>(xw_re, xw_im, uh, ul, out, gn_acc);
    k6_mlp<<<dim3(4096), dim3(256), 0, stream>>>(x, norm1_w, norm1_b, mlp_w1, mlp_b1,
                                                 mlp_w2, mlp_b2, out, gn_acc);
    k7_final<<<dim3(32768), dim3(256), 0, stream>>>(x, gamma_bc, beta_bc, gn_acc, out);
}

// Round 4
// 667.502 us; speedup vs baseline: 1.3393x; 1.0896x over previous
//
#include <hip/hip_runtime.h>
#include <math.h>

#define NB 8
#define NC 64
#define NH 256
#define NW 256
#define NHW 65536
#define NM 32
#define NPS 4194304   // C*H*W per sample
#define GN_EPS 1e-5f
#define OMEGA 0.0245436926061703f  // 2*pi/256

typedef short shortx8 __attribute__((ext_vector_type(8)));
typedef float floatx4 __attribute__((ext_vector_type(4)));

__device__ __forceinline__ float gelu_f(float v) {
    return 0.5f * v * (1.0f + erff(v * 0.7071067811865475f));
}

__device__ __forceinline__ unsigned short f2bf(float f) {
    unsigned u = __builtin_bit_cast(unsigned, f);
    u = (u + 0x7fffu + ((u >> 16) & 1u)) >> 16;
    return (unsigned short)u;
}

__device__ __forceinline__ float bf2f(unsigned short u) {
    return __builtin_bit_cast(float, ((unsigned)u) << 16);
}

// ---------------- K0: zero GN acc, FiLM gamma/beta, pack MLP weights to bf16 hi/lo
__global__ void k0_init(const float* __restrict__ t_in,
                        const float* __restrict__ gamma_w, const float* __restrict__ gamma_b,
                        const float* __restrict__ beta_w, const float* __restrict__ beta_b,
                        const float* __restrict__ mlp_w1, const float* __restrict__ mlp_w2,
                        float* __restrict__ gn_acc, float* __restrict__ gamma_bc,
                        float* __restrict__ beta_bc,
                        unsigned short* __restrict__ w1p_h, unsigned short* __restrict__ w1p_l,
                        unsigned short* __restrict__ w2p_h, unsigned short* __restrict__ w2p_l) {
    int t = threadIdx.x;
    if (t < 32) gn_acc[t] = 0.f;
    for (int idx = t; idx < NB * NC; idx += 256) {
        int b = idx >> 6, o = idx & 63;
        float g = gamma_b[o], be = beta_b[o];
        for (int c = 0; c < NC; ++c) {
            float tv = t_in[b * NC + c];
            g += gamma_w[o * NC + c] * tv;
            be += beta_w[o * NC + c] * tv;
        }
        gamma_bc[idx] = g;
        beta_bc[idx] = be;
    }
    for (int idx = t; idx < 2048; idx += 256) {
        float wv1 = mlp_w1[idx];
        unsigned short h1 = f2bf(wv1);
        w1p_h[idx] = h1;
        w1p_l[idx] = f2bf(wv1 - bf2f(h1));
        float wv2 = mlp_w2[idx];
        unsigned short h2 = f2bf(wv2);
        w2p_h[idx] = h2;
        w2p_l[idx] = f2bf(wv2 - bf2f(h2));
    }
}

// ---------------- KT: precompute all DFT twiddle matrices as bf16 hi/lo
// t1 [n=0..63][w=0..255]: n<32 cos(w*n*w'), n>=32 -sin   (K1 B^T)
// u  [w=0..255][k=0..63]: k<32 m_k*cos, k>=32 -m_k*sin   (K5 B^T, irfft doubling folded)
// m2 [m=0..127][k=0..511]: K2 A matrix. m<64: re-out row j=m: [cos | sin];
//                          m>=64: im-out row j=m-64: [-sin | cos]. f_j = j<32? j : 192+j.
// m4 [m=0..511][k=0..127]: K4 A matrix (scale 1/65536 folded). m<256: re-out h=m:
//                          [cos | -sin]; m>=256: im-out h=m-256: [sin | cos].
__global__ __launch_bounds__(256) void k_tw(unsigned short* __restrict__ t1h,
                                            unsigned short* __restrict__ t1l,
                                            unsigned short* __restrict__ uh,
                                            unsigned short* __restrict__ ul,
                                            unsigned short* __restrict__ m2h,
                                            unsigned short* __restrict__ m2l,
                                            unsigned short* __restrict__ m4h,
                                            unsigned short* __restrict__ m4l) {
    int idx = blockIdx.x * 256 + threadIdx.x;   // 0..65535
    if (idx < 16384) {
        int n = idx >> 8, w = idx & 255;
        float ph = OMEGA * (float)(((n & 31) * w) & 255);
        float s, c;
        sincosf(ph, &s, &c);
        float v = (n < 32) ? c : -s;
        unsigned short h = f2bf(v);
        t1h[idx] = h;
        t1l[idx] = f2bf(v - bf2f(h));

        int w2 = idx >> 6, k = idx & 63;
        int k31 = k & 31;
        float m = (k31 == 0) ? 1.f : 2.f;
        float ph2 = OMEGA * (float)((k31 * w2) & 255);
        sincosf(ph2, &s, &c);
        float v2 = (k < 32) ? m * c : -m * s;
        h = f2bf(v2);
        uh[idx] = h;
        ul[idx] = f2bf(v2 - bf2f(h));
    }
    {
        // m2
        int m = idx >> 9, k = idx & 511;
        int j = m & 63;
        int f = (j < 32) ? j : 192 + j;
        int h256 = k & 255;
        float s, c;
        sincosf(OMEGA * (float)((f * h256) & 255), &s, &c);
        float v = (m < 64) ? ((k < 256) ? c : s) : ((k < 256) ? -s : c);
        unsigned short hh = f2bf(v);
        m2h[idx] = hh;
        m2l[idx] = f2bf(v - bf2f(hh));
    }
    {
        // m4 (scale folded)
        const float sc = 1.0f / 65536.0f;
        int m = idx >> 7, k = idx & 127;
        int h256 = m & 255;
        int j = k & 63;
        int f = (j < 32) ? j : 192 + j;
        float s, c;
        sincosf(OMEGA * (float)((f * h256) & 255), &s, &c);
        float v = ((m < 256) ? ((k < 64) ? c : -s) : ((k < 64) ? s : c)) * sc;
        unsigned short hh = f2bf(v);
        m4h[idx] = hh;
        m4l[idx] = f2bf(v - bf2f(hh));
    }
}

// ---------------- K1: real DFT along W via split-bf16 MFMA GEMM.
__global__ __launch_bounds__(256, 4) void k1_dftw(const float* __restrict__ x,
                                                  const unsigned short* __restrict__ t1h,
                                                  const unsigned short* __restrict__ t1l,
                                                  float* __restrict__ xw_re,
                                                  float* __restrict__ xw_im) {
    __shared__ unsigned short a_h[128 * 72];
    __shared__ unsigned short a_l[128 * 72];
    int blk = blockIdx.x;          // 1024 = 512 bc * 2 row-halves
    int bc = blk >> 1;
    int h0 = (blk & 1) * 128;
    const float* src = x + (size_t)bc * NHW + (size_t)h0 * NW;
    int t = threadIdx.x;
    int lane = t & 63, wv = t >> 6, lm = lane & 15, lg = lane >> 4;

    floatx4 acc[2][4] = {};
#pragma unroll
    for (int ks = 0; ks < 4; ++ks) {
        if (ks) __syncthreads();
        for (int i = t; i < 2048; i += 256) {
            int r = i >> 4;
            int c4 = (i & 15) << 2;
            float4 v = *(const float4*)&src[(size_t)r * NW + (ks << 6) + c4];
            int off = r * 72 + c4;
            ushort4 h4, l4;
            h4.x = f2bf(v.x); l4.x = f2bf(v.x - bf2f(h4.x));
            h4.y = f2bf(v.y); l4.y = f2bf(v.y - bf2f(h4.y));
            h4.z = f2bf(v.z); l4.z = f2bf(v.z - bf2f(h4.z));
            h4.w = f2bf(v.w); l4.w = f2bf(v.w - bf2f(h4.w));
            *(ushort4*)&a_h[off] = h4;
            *(ushort4*)&a_l[off] = l4;
        }
        __syncthreads();
#pragma unroll
        for (int kk = 0; kk < 2; ++kk) {
            shortx8 ah[2], al[2], bh[4], bl[4];
#pragma unroll
            for (int mt = 0; mt < 2; ++mt) {
                int off = (wv * 32 + mt * 16 + lm) * 72 + kk * 32 + lg * 8;
                ah[mt] = *(const shortx8*)&a_h[off];
                al[mt] = *(const shortx8*)&a_l[off];
            }
#pragma unroll
            for (int nt = 0; nt < 4; ++nt) {
                int off = (nt * 16 + lm) * 256 + ks * 64 + kk * 32 + lg * 8;
                bh[nt] = *(const shortx8*)&t1h[off];
                bl[nt] = *(const shortx8*)&t1l[off];
            }
#pragma unroll
            for (int mt = 0; mt < 2; ++mt)
#pragma unroll
                for (int nt = 0; nt < 4; ++nt) {
                    acc[mt][nt] = __builtin_amdgcn_mfma_f32_16x16x32_bf16(ah[mt], bh[nt], acc[mt][nt], 0, 0, 0);
                    acc[mt][nt] = __builtin_amdgcn_mfma_f32_16x16x32_bf16(ah[mt], bl[nt], acc[mt][nt], 0, 0, 0);
                    acc[mt][nt] = __builtin_amdgcn_mfma_f32_16x16x32_bf16(al[mt], bh[nt], acc[mt][nt], 0, 0, 0);
                }
        }
    }
    size_t rowg = (size_t)bc * NH + h0;
#pragma unroll
    for (int mt = 0; mt < 2; ++mt)
#pragma unroll
        for (int nt = 0; nt < 4; ++nt) {
            int n = nt * 16 + lm;
            float* dst = (n < 32) ? xw_re : xw_im;
            int kx = n & 31;
#pragma unroll
            for (int r = 0; r < 4; ++r) {
                int row = wv * 32 + mt * 16 + lg * 4 + r;
                dst[(rowg + row) * NM + kx] = acc[mt][nt][r];
            }
        }
}

// ---------------- K2: DFT along H via split-bf16 MFMA GEMM.
// Per bc: C[m=128][n=32kx] = M2[128][512] x X^T[32][512]^T, K = (re h 0..255 | im h 0..255).
// X^T transpose-staged in LDS (pitch 520), M2 read from global (L2-resident).
__global__ __launch_bounds__(256, 2) void k2_dfth(const float* __restrict__ xw_re,
                                                  const float* __restrict__ xw_im,
                                                  const unsigned short* __restrict__ m2h,
                                                  const unsigned short* __restrict__ m2l,
                                                  float* __restrict__ xf_re,
                                                  float* __restrict__ xf_im) {
    __shared__ unsigned short bt_h[32 * 520];
    __shared__ unsigned short bt_l[32 * 520];
    int bc = blockIdx.x;
    size_t base = (size_t)bc * (NH * NM);
    int t = threadIdx.x;
    for (int idx4 = t; idx4 < 2048; idx4 += 256) {
        int h = idx4 >> 3;
        int kxg = (idx4 & 7) << 2;
        float4 vr = ((const float4*)(xw_re + base))[idx4];
        float4 vi = ((const float4*)(xw_im + base))[idx4];
        float fr[4] = {vr.x, vr.y, vr.z, vr.w};
        float fi[4] = {vi.x, vi.y, vi.z, vi.w};
#pragma unroll
        for (int q = 0; q < 4; ++q) {
            int rowo = (kxg + q) * 520;
            unsigned short hh = f2bf(fr[q]);
            bt_h[rowo + h] = hh;
            bt_l[rowo + h] = f2bf(fr[q] - bf2f(hh));
            hh = f2bf(fi[q]);
            bt_h[rowo + 256 + h] = hh;
            bt_l[rowo + 256 + h] = f2bf(fi[q] - bf2f(hh));
        }
    }
    __syncthreads();

    int lane = t & 63, wv = t >> 6, lm = lane & 15, lg = lane >> 4;
    floatx4 acc[2][2] = {};
#pragma unroll
    for (int ks = 0; ks < 16; ++ks) {
        shortx8 bh[2], bl[2], ah[2], al[2];
#pragma unroll
        for (int nt = 0; nt < 2; ++nt) {
            int off = (nt * 16 + lm) * 520 + ks * 32 + lg * 8;
            bh[nt] = *(const shortx8*)&bt_h[off];
            bl[nt] = *(const shortx8*)&bt_l[off];
        }
#pragma unroll
        for (int mt = 0; mt < 2; ++mt) {
            int off = (wv * 32 + mt * 16 + lm) * 512 + ks * 32 + lg * 8;
            ah[mt] = *(const shortx8*)&m2h[off];
            al[mt] = *(const shortx8*)&m2l[off];
        }
#pragma unroll
        for (int mt = 0; mt < 2; ++mt)
#pragma unroll
            for (int nt = 0; nt < 2; ++nt) {
                acc[mt][nt] = __builtin_amdgcn_mfma_f32_16x16x32_bf16(ah[mt], bh[nt], acc[mt][nt], 0, 0, 0);
                acc[mt][nt] = __builtin_amdgcn_mfma_f32_16x16x32_bf16(ah[mt], bl[nt], acc[mt][nt], 0, 0, 0);
                acc[mt][nt] = __builtin_amdgcn_mfma_f32_16x16x32_bf16(al[mt], bh[nt], acc[mt][nt], 0, 0, 0);
            }
    }
    size_t ob = (size_t)bc * 2048;
#pragma unroll
    for (int mt = 0; mt < 2; ++mt)
#pragma unroll
        for (int nt = 0; nt < 2; ++nt) {
            int n = nt * 16 + lm;
#pragma unroll
            for (int r = 0; r < 4; ++r) {
                int row = wv * 32 + mt * 16 + lg * 4 + r;
                float* dst = (row < 64) ? xf_re : xf_im;
                dst[ob + (row & 63) * 32 + n] = acc[mt][nt][r];
            }
        }
}

// ---------------- K3: per-mode complex channel mix.  Yf[b][o][ky][kx]
__global__ __launch_bounds__(256) void k3_mix(const float* __restrict__ xf_re,
                                              const float* __restrict__ xf_im,
                                              const float* __restrict__ w1r, const float* __restrict__ w1i,
                                              const float* __restrict__ w2r, const float* __restrict__ w2i,
                                              float* __restrict__ yf_re, float* __restrict__ yf_im) {
    __shared__ float xr_l[4 * 64 * 32];
    __shared__ float xi_l[4 * 64 * 32];
    int blk = blockIdx.x;          // ((ky*8 + oct)*2 + bh)
    int bh = blk & 1;
    int oct = (blk >> 1) & 7;
    int ky = blk >> 4;
    for (int idx = threadIdx.x; idx < 4 * 64 * 32; idx += 256) {
        int bb = idx >> 11;
        int i = (idx >> 5) & 63;
        int kx = idx & 31;
        size_t g = ((size_t)((bh * 4 + bb) * 64 + i) * 64 + ky) * 32 + kx;
        xr_l[idx] = xf_re[g];
        xi_l[idx] = xf_im[g];
    }
    __syncthreads();
    const float* wr = (ky < 32) ? w1r : w2r;
    const float* wi = (ky < 32) ? w1i : w2i;
    int kyl = ky & 31;
    int t = threadIdx.x;
    int kx = t & 31, oo = t >> 5;
    int o = oct * 8 + oo;
    float accr[4] = {0.f, 0.f, 0.f, 0.f};
    float acci[4] = {0.f, 0.f, 0.f, 0.f};
    for (int i = 0; i < 64; ++i) {
        size_t wbase = ((size_t)(i * 64 + o) * 32 + kyl) * 32 + kx;
        float wrv = wr[wbase];
        float wiv = wi[wbase];
#pragma unroll
        for (int bb = 0; bb < 4; ++bb) {
            float xr = xr_l[(bb * 64 + i) * 32 + kx];
            float xi = xi_l[(bb * 64 + i) * 32 + kx];
            accr[bb] += xr * wrv - xi * wiv;
            acci[bb] += xr * wiv + xi * wrv;
        }
    }
#pragma unroll
    for (int bb = 0; bb < 4; ++bb) {
        int b = bh * 4 + bb;
        size_t g = ((size_t)(b * 64 + o) * 64 + ky) * 32 + kx;
        yf_re[g] = accr[bb];
        yf_im[g] = acci[bb];
    }
}

// ---------------- K4: inverse DFT along H via split-bf16 MFMA GEMM.
// Per bc: C[m=512][n=32kx] = M4[512][128] x Y^T, K = (yr j 0..63 | yi j 0..63).
// m<256 -> yh_re[h=m], m>=256 -> yh_im[h=m-256]. Scale 1/65536 folded into M4.
__global__ __launch_bounds__(256, 2) void k4_idfth(const float* __restrict__ yf_re,
                                                   const float* __restrict__ yf_im,
                                                   const unsigned short* __restrict__ m4h,
                                                   const unsigned short* __restrict__ m4l,
                                                   float* __restrict__ yh_re,
                                                   float* __restrict__ yh_im) {
    __shared__ unsigned short bt_h[32 * 136];
    __shared__ unsigned short bt_l[32 * 136];
    int bc = blockIdx.x;
    size_t base = (size_t)bc * 2048;
    int t = threadIdx.x;
    for (int idx4 = t; idx4 < 512; idx4 += 256) {
        int j = idx4 >> 3;
        int kxg = (idx4 & 7) << 2;
        float4 vr = ((const float4*)(yf_re + base))[idx4];
        float4 vi = ((const float4*)(yf_im + base))[idx4];
        float fr[4] = {vr.x, vr.y, vr.z, vr.w};
        float fi[4] = {vi.x, vi.y, vi.z, vi.w};
#pragma unroll
        for (int q = 0; q < 4; ++q) {
            int rowo = (kxg + q) * 136;
            unsigned short hh = f2bf(fr[q]);
            bt_h[rowo + j] = hh;
            bt_l[rowo + j] = f2bf(fr[q] - bf2f(hh));
            hh = f2bf(fi[q]);
            bt_h[rowo + 64 + j] = hh;
            bt_l[rowo + 64 + j] = f2bf(fi[q] - bf2f(hh));
        }
    }
    __syncthreads();

    int lane = t & 63, wv = t >> 6, lm = lane & 15, lg = lane >> 4;
    floatx4 acc[8][2] = {};
#pragma unroll
    for (int ks = 0; ks < 4; ++ks) {
        shortx8 bh[2], bl[2];
#pragma unroll
        for (int nt = 0; nt < 2; ++nt) {
            int off = (nt * 16 + lm) * 136 + ks * 32 + lg * 8;
            bh[nt] = *(const shortx8*)&bt_h[off];
            bl[nt] = *(const shortx8*)&bt_l[off];
        }
#pragma unroll
        for (int mt = 0; mt < 8; ++mt) {
            int off = (wv * 128 + mt * 16 + lm) * 128 + ks * 32 + lg * 8;
            shortx8 ah = *(const shortx8*)&m4h[off];
            shortx8 al = *(const shortx8*)&m4l[off];
#pragma unroll
            for (int nt = 0; nt < 2; ++nt) {
                acc[mt][nt] = __builtin_amdgcn_mfma_f32_16x16x32_bf16(ah, bh[nt], acc[mt][nt], 0, 0, 0);
                acc[mt][nt] = __builtin_amdgcn_mfma_f32_16x16x32_bf16(ah, bl[nt], acc[mt][nt], 0, 0, 0);
                acc[mt][nt] = __builtin_amdgcn_mfma_f32_16x16x32_bf16(al, bh[nt], acc[mt][nt], 0, 0, 0);
            }
        }
    }
    size_t ob = (size_t)bc * (NH * NM);
#pragma unroll
    for (int mt = 0; mt < 8; ++mt)
#pragma unroll
        for (int nt = 0; nt < 2; ++nt) {
            int n = nt * 16 + lm;
#pragma unroll
            for (int r = 0; r < 4; ++r) {
                int row = wv * 128 + mt * 16 + lg * 4 + r;
                float* dst = (row < 256) ? yh_re : yh_im;
                dst[ob + (row & 255) * 32 + n] = acc[mt][nt][r];
            }
        }
}

// ---------------- K5: inverse real DFT along W via split-bf16 MFMA + GN1 stats.
__global__ __launch_bounds__(256, 2) void k5_irfftw(const float* __restrict__ yh_re,
                                                    const float* __restrict__ yh_im,
                                                    const unsigned short* __restrict__ uh,
                                                    const unsigned short* __restrict__ ul,
                                                    float* __restrict__ yout,
                                                    float* __restrict__ gn_acc) {
    __shared__ unsigned short a_h[128 * 72];
    __shared__ unsigned short a_l[128 * 72];
    __shared__ float red[8];
    int blk = blockIdx.x;          // 1024 blocks of 128 rows
    size_t row0 = (size_t)blk * 128;
    int t = threadIdx.x;

    for (int i = t; i < 1024; i += 256) {
        int r = i >> 3;
        int c4 = (i & 7) << 2;
        float4 vr = *(const float4*)&yh_re[(row0 + r) * NM + c4];
        float4 vi = *(const float4*)&yh_im[(row0 + r) * NM + c4];
        int offr = r * 72 + c4;
        ushort4 h4, l4;
        h4.x = f2bf(vr.x); l4.x = f2bf(vr.x - bf2f(h4.x));
        h4.y = f2bf(vr.y); l4.y = f2bf(vr.y - bf2f(h4.y));
        h4.z = f2bf(vr.z); l4.z = f2bf(vr.z - bf2f(h4.z));
        h4.w = f2bf(vr.w); l4.w = f2bf(vr.w - bf2f(h4.w));
        *(ushort4*)&a_h[offr] = h4;
        *(ushort4*)&a_l[offr] = l4;
        h4.x = f2bf(vi.x); l4.x = f2bf(vi.x - bf2f(h4.x));
        h4.y = f2bf(vi.y); l4.y = f2bf(vi.y - bf2f(h4.y));
        h4.z = f2bf(vi.z); l4.z = f2bf(vi.z - bf2f(h4.z));
        h4.w = f2bf(vi.w); l4.w = f2bf(vi.w - bf2f(h4.w));
        *(ushort4*)&a_h[offr + 32] = h4;
        *(ushort4*)&a_l[offr + 32] = l4;
    }
    __syncthreads();

    int lane = t & 63, wv = t >> 6, lm = lane & 15, lg = lane >> 4;
    floatx4 acc[2][16] = {};
#pragma unroll
    for (int kk = 0; kk < 2; ++kk) {
        shortx8 ah[2], al[2];
#pragma unroll
        for (int mt = 0; mt < 2; ++mt) {
            int off = (wv * 32 + mt * 16 + lm) * 72 + kk * 32 + lg * 8;
            ah[mt] = *(const shortx8*)&a_h[off];
            al[mt] = *(const shortx8*)&a_l[off];
        }
#pragma unroll
        for (int nt = 0; nt < 16; ++nt) {
            int w = nt * 16 + lm;
            shortx8 bh = *(const shortx8*)&uh[w * 64 + kk * 32 + lg * 8];
            shortx8 bl = *(const shortx8*)&ul[w * 64 + kk * 32 + lg * 8];
#pragma unroll
            for (int mt = 0; mt < 2; ++mt) {
                acc[mt][nt] = __builtin_amdgcn_mfma_f32_16x16x32_bf16(ah[mt], bh, acc[mt][nt], 0, 0, 0);
                acc[mt][nt] = __builtin_amdgcn_mfma_f32_16x16x32_bf16(ah[mt], bl, acc[mt][nt], 0, 0, 0);
                acc[mt][nt] = __builtin_amdgcn_mfma_f32_16x16x32_bf16(al[mt], bh, acc[mt][nt], 0, 0, 0);
            }
        }
    }

    float sum = 0.f, sq = 0.f;
#pragma unroll
    for (int mt = 0; mt < 2; ++mt)
#pragma unroll
        for (int nt = 0; nt < 16; ++nt) {
            int w = nt * 16 + lm;
#pragma unroll
            for (int r = 0; r < 4; ++r) {
                int row = wv * 32 + mt * 16 + lg * 4 + r;
                float v = acc[mt][nt][r];
                yout[(row0 + row) * NW + w] = v;
                sum += v;
                sq += v * v;
            }
        }
#pragma unroll
    for (int off = 32; off > 0; off >>= 1) {
        sum += __shfl_down(sum, off);
        sq += __shfl_down(sq, off);
    }
    if (lane == 0) { red[wv] = sum; red[4 + wv] = sq; }
    __syncthreads();
    if (t == 0) {
        int b = blk >> 7;
        atomicAdd(&gn_acc[b * 4 + 0], red[0] + red[1] + red[2] + red[3]);
        atomicAdd(&gn_acc[b * 4 + 1], red[4] + red[5] + red[6] + red[7]);
    }
}

// ---------------- K6: GN1 + residual + gelu + MLP via SPLIT-BF16 MFMA + GN2 stats
// This round: stage-1 float4 loads (16B/lane), weights pre-split in workspace.
__global__ __launch_bounds__(256, 2) void k6_mlp(const float* __restrict__ x,
                                                 const float* __restrict__ norm1_w,
                                                 const float* __restrict__ norm1_b,
                                                 const unsigned short* __restrict__ w1p_h,
                                                 const unsigned short* __restrict__ w1p_l,
                                                 const unsigned short* __restrict__ w2p_h,
                                                 const unsigned short* __restrict__ w2p_l,
                                                 const float* __restrict__ mlp_b1,
                                                 const float* __restrict__ mlp_b2,
                                                 float* __restrict__ y,
                                                 float* __restrict__ gn_acc) {
    __shared__ __align__(16) unsigned char smem[77728];
    unsigned short* vbuf_h = (unsigned short*)smem;
    unsigned short* vbuf_l = (unsigned short*)(smem + 18432);
    unsigned short* w1_h   = (unsigned short*)(smem + 36864);
    unsigned short* w1_l   = (unsigned short*)(smem + 41472);
    unsigned short* hbuf_h = (unsigned short*)(smem + 46080);
    unsigned short* hbuf_l = (unsigned short*)(smem + 56320);
    unsigned short* w2_h   = (unsigned short*)(smem + 66560);
    unsigned short* w2_l   = (unsigned short*)(smem + 71680);
    float* outbuf = (float*)smem;                 // alias (phase 2)
    float* nwl = (float*)(smem + 76800);
    float* nbl = nwl + 64;
    float* b1l = nbl + 64;
    float* b2l = b1l + 32;
    float* red = b2l + 64;

    int t = threadIdx.x;
    int blk = blockIdx.x;
    int b = blk >> 9;                  // 512 blocks per sample
    int pixbase = (blk & 511) * 128;
    size_t bbase = (size_t)b * NC * NHW + pixbase;

    if (t < 64) { nwl[t] = norm1_w[t]; nbl[t] = norm1_b[t]; b2l[t] = mlp_b2[t]; }
    if (t >= 64 && t < 96) b1l[t - 64] = mlp_b1[t - 64];
    // weights: pre-split ushort4 copies into pitched LDS
#pragma unroll
    for (int idx4 = t; idx4 < 512; idx4 += 256) {
        int r1 = idx4 >> 4, c1 = (idx4 & 15) << 2;
        *(ushort4*)&w1_h[r1 * 72 + c1] = ((const ushort4*)w1p_h)[idx4];
        *(ushort4*)&w1_l[r1 * 72 + c1] = ((const ushort4*)w1p_l)[idx4];
        int r2 = idx4 >> 3, c2 = (idx4 & 7) << 2;
        *(ushort4*)&w2_h[r2 * 40 + c2] = ((const ushort4*)w2p_h)[idx4];
        *(ushort4*)&w2_l[r2 * 40 + c2] = ((const ushort4*)w2p_l)[idx4];
    }
    __syncthreads();   // params/weights visible before stage 1

    // --- stage 1: v = gelu(gn1(y)*nw+nb + x), float4 loads, bf16 hi/lo to vbuf[pix][c]
    const float invN = 1.0f / (float)NPS;
    float m1 = gn_acc[b * 4 + 0] * invN;
    float var1 = gn_acc[b * 4 + 1] * invN - m1 * m1;
    float rs1 = rsqrtf(var1 + GN_EPS);
    {
        int pg = (t & 31) << 2;        // pixel group (4 consecutive)
        int cg = (t >> 5) << 3;        // 8 channels per thread
#pragma unroll
        for (int ci = 0; ci < 8; ++ci) {
            int c = cg + ci;
            size_t rb = bbase + (size_t)c * NHW + pg;
            float4 yv4 = *(const float4*)&y[rb];
            float4 xv4 = *(const float4*)&x[rb];
            float nw = nwl[c], nb = nbl[c];
            float gv[4];
            gv[0] = gelu_f((yv4.x - m1) * rs1 * nw + nb + xv4.x);
            gv[1] = gelu_f((yv4.y - m1) * rs1 * nw + nb + xv4.y);
            gv[2] = gelu_f((yv4.z - m1) * rs1 * nw + nb + xv4.z);
            gv[3] = gelu_f((yv4.w - m1) * rs1 * nw + nb + xv4.w);
#pragma unroll
            for (int q = 0; q < 4; ++q) {
                unsigned short vh = f2bf(gv[q]);
                vbuf_h[(pg + q) * 72 + c] = vh;
                vbuf_l[(pg + q) * 72 + c] = f2bf(gv[q] - bf2f(vh));
            }
        }
    }
    __syncthreads();

    int lane = t & 63, wv = t >> 6;
    int lm = lane & 15, lg = lane >> 4;

    floatx4 acc1[2][2] = {};
#pragma unroll
    for (int ks = 0; ks < 2; ++ks) {
        shortx8 ah[2], al[2], bh[2], bl[2];
#pragma unroll
        for (int mt = 0; mt < 2; ++mt) {
            int off = (wv * 32 + mt * 16 + lm) * 72 + lg * 8 + ks * 32;
            ah[mt] = *(const shortx8*)&vbuf_h[off];
            al[mt] = *(const shortx8*)&vbuf_l[off];
        }
#pragma unroll
        for (int nt = 0; nt < 2; ++nt) {
            int off = (nt * 16 + lm) * 72 + lg * 8 + ks * 32;
            bh[nt] = *(const shortx8*)&w1_h[off];
            bl[nt] = *(const shortx8*)&w1_l[off];
        }
#pragma unroll
        for (int mt = 0; mt < 2; ++mt)
#pragma unroll
            for (int nt = 0; nt < 2; ++nt) {
                acc1[mt][nt] = __builtin_amdgcn_mfma_f32_16x16x32_bf16(ah[mt], bh[nt], acc1[mt][nt], 0, 0, 0);
                acc1[mt][nt] = __builtin_amdgcn_mfma_f32_16x16x32_bf16(ah[mt], bl[nt], acc1[mt][nt], 0, 0, 0);
                acc1[mt][nt] = __builtin_amdgcn_mfma_f32_16x16x32_bf16(al[mt], bh[nt], acc1[mt][nt], 0, 0, 0);
            }
    }
#pragma unroll
    for (int mt = 0; mt < 2; ++mt)
#pragma unroll
        for (int nt = 0; nt < 2; ++nt) {
            float b1v = b1l[nt * 16 + lm];
#pragma unroll
            for (int r = 0; r < 4; ++r) {
                float hv = gelu_f(acc1[mt][nt][r] + b1v);
                unsigned short hh = f2bf(hv);
                int off = (wv * 32 + mt * 16 + lg * 4 + r) * 40 + nt * 16 + lm;
                hbuf_h[off] = hh;
                hbuf_l[off] = f2bf(hv - bf2f(hh));
            }
        }
    __syncthreads();

    floatx4 acc2[2][4] = {};
    {
        shortx8 ah2[2], al2[2], bh2[4], bl2[4];
#pragma unroll
        for (int mt = 0; mt < 2; ++mt) {
            int off = (wv * 32 + mt * 16 + lm) * 40 + lg * 8;
            ah2[mt] = *(const shortx8*)&hbuf_h[off];
            al2[mt] = *(const shortx8*)&hbuf_l[off];
        }
#pragma unroll
        for (int nt = 0; nt < 4; ++nt) {
            int off = (nt * 16 + lm) * 40 + lg * 8;
            bh2[nt] = *(const shortx8*)&w2_h[off];
            bl2[nt] = *(const shortx8*)&w2_l[off];
        }
#pragma unroll
        for (int mt = 0; mt < 2; ++mt)
#pragma unroll
            for (int nt = 0; nt < 4; ++nt) {
                acc2[mt][nt] = __builtin_amdgcn_mfma_f32_16x16x32_bf16(ah2[mt], bh2[nt], acc2[mt][nt], 0, 0, 0);
                acc2[mt][nt] = __builtin_amdgcn_mfma_f32_16x16x32_bf16(ah2[mt], bl2[nt], acc2[mt][nt], 0, 0, 0);
                acc2[mt][nt] = __builtin_amdgcn_mfma_f32_16x16x32_bf16(al2[mt], bh2[nt], acc2[mt][nt], 0, 0, 0);
            }
    }
    __syncthreads();   // all hbuf/w2buf reads done; outbuf may now clobber

#pragma unroll
    for (int mt = 0; mt < 2; ++mt)
#pragma unroll
        for (int nt = 0; nt < 4; ++nt) {
            int ch = nt * 16 + lm;
            float b2v = b2l[ch];
#pragma unroll
            for (int r = 0; r < 4; ++r)
                outbuf[ch * 132 + wv * 32 + mt * 16 + lg * 4 + r] = acc2[mt][nt][r] + b2v;
        }
    __syncthreads();

    float sum = 0.f, sq = 0.f;
#pragma unroll
    for (int it = 0; it < 8; ++it) {
        int flat = it * 256 + t;
        int c = flat >> 5;
        int p4 = (flat & 31) * 4;
        float4 v = *(const float4*)&outbuf[c * 132 + p4];
        *(float4*)&y[bbase + (size_t)c * NHW + p4] = v;
        sum += v.x + v.y + v.z + v.w;
        sq += v.x * v.x + v.y * v.y + v.z * v.z + v.w * v.w;
    }
#pragma unroll
    for (int off = 32; off > 0; off >>= 1) {
        sum += __shfl_down(sum, off);
        sq += __shfl_down(sq, off);
    }
    if (lane == 0) { red[wv] = sum; red[4 + wv] = sq; }
    __syncthreads();
    if (t == 0) {
        atomicAdd(&gn_acc[b * 4 + 2], red[0] + red[1] + red[2] + red[3]);
        atomicAdd(&gn_acc[b * 4 + 3], red[4] + red[5] + red[6] + red[7]);
    }
}

// ---------------- K7: GN2 + FiLM + gelu(x) skip, elementwise, in-place
__global__ __launch_bounds__(256) void k7_final(const float* __restrict__ x,
                                                const float* __restrict__ gamma_bc,
                                                const float* __restrict__ beta_bc,
                                                const float* __restrict__ gn_acc,
                                                float* __restrict__ y) {
    size_t idx4 = (size_t)blockIdx.x * 256 + threadIdx.x;
    size_t base = idx4 * 4;
    int b = (int)(base >> 22);
    int c = (int)((base >> 16) & 63);
    const float invN = 1.0f / (float)NPS;
    float m2 = gn_acc[b * 4 + 2] * invN;
    float var2 = gn_acc[b * 4 + 3] * invN - m2 * m2;
    float rs2 = rsqrtf(var2 + GN_EPS);
    float g = gamma_bc[b * 64 + c];
    float be = beta_bc[b * 64 + c];
    float4 yv = ((float4*)y)[idx4];
    float4 xv = ((const float4*)x)[idx4];
    yv.x = g * ((yv.x - m2) * rs2) + be + gelu_f(xv.x);
    yv.y = g * ((yv.y - m2) * rs2) + be + gelu_f(xv.y);
    yv.z = g * ((yv.z - m2) * rs2) + be + gelu_f(xv.z);
    yv.w = g * ((yv.w - m2) * rs2) + be + gelu_f(xv.w);
    ((float4*)y)[idx4] = yv;
}

extern "C" void kernel_launch(void* const* d_in, const int* in_sizes, int n_in,
                              void* d_out, int out_size, void* d_ws, size_t ws_size,
                              hipStream_t stream) {
    (void)in_sizes; (void)n_in; (void)out_size; (void)ws_size;
    const float* x       = (const float*)d_in[0];
    const float* t_in    = (const float*)d_in[1];
    const float* w1r     = (const float*)d_in[2];
    const float* w1i     = (const float*)d_in[3];
    const float* w2r     = (const float*)d_in[4];
    const float* w2i     = (const float*)d_in[5];
    const float* norm1_w = (const float*)d_in[6];
    const float* norm1_b = (const float*)d_in[7];
    const float* mlp_w1  = (const float*)d_in[8];
    const float* mlp_b1  = (const float*)d_in[9];
    const float* mlp_w2  = (const float*)d_in[10];
    const float* mlp_b2  = (const float*)d_in[11];
    const float* gamma_w = (const float*)d_in[12];
    const float* gamma_b = (const float*)d_in[13];
    const float* beta_w  = (const float*)d_in[14];
    const float* beta_b  = (const float*)d_in[15];
    float* out = (float*)d_out;
    float* ws  = (float*)d_ws;

    float* gn_acc   = ws;            // 32
    float* gamma_bc = ws + 32;       // 512
    float* beta_bc  = ws + 544;      // 512
    float* xw_re    = ws + 2048;     // 4194304
    float* xw_im    = xw_re + 4194304;
    float* xf_re    = xw_im + 4194304;  // 1048576
    float* xf_im    = xf_re + 1048576;
    float* yf_re    = xf_im + 1048576;
    float* yf_im    = yf_re + 1048576;
    unsigned short* t1h = (unsigned short*)(yf_im + 1048576);
    unsigned short* t1l = t1h + 16384;
    unsigned short* uh  = t1l + 16384;
    unsigned short* ul  = uh + 16384;
    unsigned short* w1p_h = ul + 16384;     // 2048 each
    unsigned short* w1p_l = w1p_h + 2048;
    unsigned short* w2p_h = w1p_l + 2048;
    unsigned short* w2p_l = w2p_h + 2048;
    unsigned short* m2h = w2p_l + 2048;     // 65536 each
    unsigned short* m2l = m2h + 65536;
    unsigned short* m4h = m2l + 65536;
    unsigned short* m4l = m4h + 65536;

    k_tw<<<dim3(256), dim3(256), 0, stream>>>(t1h, t1l, uh, ul, m2h, m2l, m4h, m4l);
    k0_init<<<dim3(1), dim3(256), 0, stream>>>(t_in, gamma_w, gamma_b, beta_w, beta_b,
                                               mlp_w1, mlp_w2,
                                               gn_acc, gamma_bc, beta_bc,
                                               w1p_h, w1p_l, w2p_h, w2p_l);
    k1_dftw<<<dim3(1024), dim3(256), 0, stream>>>(x, t1h, t1l, xw_re, xw_im);
    k2_dfth<<<dim3(512), dim3(256), 0, stream>>>(xw_re, xw_im, m2h, m2l, xf_re, xf_im);
    k3_mix<<<dim3(1024), dim3(256), 0, stream>>>(xf_re, xf_im, w1r, w1i, w2r, w2i,
                                                 yf_re, yf_im);
    k4_idfth<<<dim3(512), dim3(256), 0, stream>>>(yf_re, yf_im, m4h, m4l, xw_re, xw_im);
    k5_irfftw<<<dim3(1024), dim3(256), 0, stream>>>(xw_re, xw_im, uh, ul, out, gn_acc);
    k6_mlp<<<dim3(4096), dim3(256), 0, stream>>>(x, norm1_w, norm1_b,
                                                 w1p_h, w1p_l, w2p_h, w2p_l,
                                                 mlp_b1, mlp_b2, out, gn_acc);
    k7_final<<<dim3(32768), dim3(256), 0, stream>>>(x, gamma_bc, beta_bc, gn_acc, out);
}